// Round 7
// baseline (41388.400 us; speedup 1.0000x reference)
//
#include <hip/hip_runtime.h>
#include <hip/hip_bf16.h>
#include <cstdint>
#include <cstddef>

// Problem constants
#define TT 512
#define BB 32
#define DD 1024
#define HH 1024
#define SS 512

typedef _Float16 f16x8 __attribute__((ext_vector_type(8)));
typedef _Float16 f16x4 __attribute__((ext_vector_type(4)));
typedef _Float16 f16x2 __attribute__((ext_vector_type(2)));
typedef float f32x4 __attribute__((ext_vector_type(4)));

__device__ __forceinline__ float sigm(float x) { return 1.0f / (1.0f + __expf(-x)); }
__device__ __forceinline__ float tanh_fast(float x) {
    return 1.0f - 2.0f / (__expf(2.0f * x) + 1.0f);  // saturates, no inf/inf
}
// load 8 contiguous fp32, round to fp16 MFMA fragment
__device__ __forceinline__ f16x8 cvt8(const float* __restrict__ p) {
    float4 u = *(const float4*)p;
    float4 v = *(const float4*)(p + 4);
    f16x8 r;
    r[0] = (_Float16)u.x; r[1] = (_Float16)u.y; r[2] = (_Float16)u.z; r[3] = (_Float16)u.w;
    r[4] = (_Float16)v.x; r[5] = (_Float16)v.y; r[6] = (_Float16)v.z; r[7] = (_Float16)v.w;
    return r;
}

// ---------------------------------------------------------------------------
// Cache-bypassing (coherent-point) access helpers for cross-block RAW data.
// Relaxed agent-scope atomics bypass per-XCD L1/L2 -> MALL directly.
// ---------------------------------------------------------------------------
__device__ __forceinline__ void st_u32_coh(unsigned* p, unsigned v) {
    __hip_atomic_store(p, v, __ATOMIC_RELAXED, __HIP_MEMORY_SCOPE_AGENT);
}
__device__ __forceinline__ unsigned ld_u32_coh(const unsigned* p) {
    return __hip_atomic_load(p, __ATOMIC_RELAXED, __HIP_MEMORY_SCOPE_AGENT);
}
__device__ __forceinline__ unsigned long long ld_u64_coh(const unsigned long long* p) {
    return __hip_atomic_load(p, __ATOMIC_RELAXED, __HIP_MEMORY_SCOPE_AGENT);
}
__device__ __forceinline__ f16x8 ld16_coh(const _Float16* p) {
    union { unsigned long long q[2]; f16x8 h; } u;
    u.q[0] = ld_u64_coh((const unsigned long long*)p);
    u.q[1] = ld_u64_coh((const unsigned long long*)p + 1);
    return u.h;
}

// ---------------------------------------------------------------------------
// staging: fp32 -> fp16 copy (grid-stride, float4 -> f16x4)
// ---------------------------------------------------------------------------
__global__ __launch_bounds__(256) void k_cvt(const float* __restrict__ s,
                                             _Float16* __restrict__ d, int n4) {
    for (int i = blockIdx.x * blockDim.x + threadIdx.x; i < n4; i += gridDim.x * blockDim.x) {
        float4 v = ((const float4*)s)[i];
        f16x4 h;
        h[0] = (_Float16)v.x; h[1] = (_Float16)v.y;
        h[2] = (_Float16)v.z; h[3] = (_Float16)v.w;
        ((f16x4*)d)[i] = h;
    }
}

__global__ void k_bias(const float* __restrict__ bih, const float* __restrict__ bhh,
                       float* __restrict__ bsum) {
    const int i = blockIdx.x * blockDim.x + threadIdx.x;
    if (i < 4 * HH) bsum[i] = bih[i] + bhh[i];
}

__global__ void k_init(const float* __restrict__ c0, float* __restrict__ cbuf) {
    const int i = blockIdx.x * blockDim.x + threadIdx.x;
    if (i < BB * HH) cbuf[i] = c0[i];
}

// zero the WHOLE barrier region (stale values from a previous graph replay
// would make every barrier fall through).
__global__ void k_zero(unsigned* __restrict__ p) {
    const int i = blockIdx.x * blockDim.x + threadIdx.x;
    if (i < 1024) p[i] = 0u;
}

__global__ void k_fin(const float* __restrict__ lasth, const float* __restrict__ cbuf,
                      float* __restrict__ hT, float* __restrict__ cT) {
    const int i = blockIdx.x * blockDim.x + threadIdx.x;
    if (i < BB * HH) {
        hT[i] = lasth[i];
        cT[i] = cbuf[i];
    }
}

// ---------------------------------------------------------------------------
// K_pre (old path only)
// ---------------------------------------------------------------------------
__global__ __launch_bounds__(256) void k_pre(const float* __restrict__ x,
                                             const float* __restrict__ Wih,
                                             _Float16* __restrict__ gx) {
    const int wave = (blockIdx.x * blockDim.x + threadIdx.x) >> 6;
    const int lane = threadIdx.x & 63;
    const int m0 = (wave >> 6) * 64, n0 = (wave & 63) * 64;
    const int lm = lane & 15, q8 = (lane >> 4) * 8;

    f32x4 acc[4][4];
    #pragma unroll
    for (int i = 0; i < 4; ++i)
        #pragma unroll
        for (int j = 0; j < 4; ++j) acc[i][j] = (f32x4)0.0f;

    for (int k0 = 0; k0 < DD; k0 += 32) {
        f16x8 a[4], b[4];
        #pragma unroll
        for (int i = 0; i < 4; ++i)
            a[i] = cvt8(x + (size_t)(m0 + i * 16 + lm) * DD + k0 + q8);
        #pragma unroll
        for (int j = 0; j < 4; ++j)
            b[j] = cvt8(Wih + (size_t)(n0 + j * 16 + lm) * DD + k0 + q8);
        #pragma unroll
        for (int i = 0; i < 4; ++i)
            #pragma unroll
            for (int j = 0; j < 4; ++j)
                acc[i][j] = __builtin_amdgcn_mfma_f32_16x16x32_f16(a[i], b[j], acc[i][j], 0, 0, 0);
    }
    const int rq = (lane >> 4) * 4;
    #pragma unroll
    for (int i = 0; i < 4; ++i)
        #pragma unroll
        for (int j = 0; j < 4; ++j)
            #pragma unroll
            for (int r = 0; r < 4; ++r)
                gx[(size_t)(m0 + i * 16 + rq + r) * (4 * HH) + n0 + j * 16 + lm] =
                    (_Float16)acc[i][j][r];
}

// ---------------------------------------------------------------------------
// k_trwin: WinT[k][j] = Win[j][k] as fp16 (one-time, for ctxW GEMM)
// ---------------------------------------------------------------------------
__global__ __launch_bounds__(256) void k_trwin(const float* __restrict__ Win,
                                               _Float16* __restrict__ WinT) {
    __shared__ float tile[32][33];
    const int bx = blockIdx.x & 31, by = blockIdx.x >> 5;
    const int tx = threadIdx.x & 31, ty = threadIdx.x >> 5;
    #pragma unroll
    for (int r = 0; r < 4; ++r)
        tile[ty + r * 8][tx] = Win[(size_t)(by * 32 + ty + r * 8) * HH + bx * 32 + tx];
    __syncthreads();
    #pragma unroll
    for (int r = 0; r < 4; ++r)
        WinT[(size_t)(bx * 32 + ty + r * 8) * HH + by * 32 + tx] =
            (_Float16)tile[tx][ty + r * 8];
}

// ---------------------------------------------------------------------------
// k_ctxw: ctxW[(s,b),k] = sum_j ctx[(s,b),j] * WinT[k,j]  (= ctx @ Win)
// ---------------------------------------------------------------------------
__global__ __launch_bounds__(256) void k_ctxw(const float* __restrict__ ctxf,
                                              const _Float16* __restrict__ WinT,
                                              _Float16* __restrict__ ctxW) {
    const int wave = (blockIdx.x * blockDim.x + threadIdx.x) >> 6;  // 4096 waves
    const int lane = threadIdx.x & 63;
    const int m0 = (wave >> 4) * 64, n0 = (wave & 15) * 64;
    const int lm = lane & 15, q8 = (lane >> 4) * 8;

    f32x4 acc[4][4];
    #pragma unroll
    for (int i = 0; i < 4; ++i)
        #pragma unroll
        for (int j = 0; j < 4; ++j) acc[i][j] = (f32x4)0.0f;

    for (int k0 = 0; k0 < HH; k0 += 32) {
        f16x8 a[4], b[4];
        #pragma unroll
        for (int i = 0; i < 4; ++i)
            a[i] = cvt8(ctxf + (size_t)(m0 + i * 16 + lm) * HH + k0 + q8);
        #pragma unroll
        for (int j = 0; j < 4; ++j)
            b[j] = *(const f16x8*)(WinT + (size_t)(n0 + j * 16 + lm) * HH + k0 + q8);
        #pragma unroll
        for (int i = 0; i < 4; ++i)
            #pragma unroll
            for (int j = 0; j < 4; ++j)
                acc[i][j] = __builtin_amdgcn_mfma_f32_16x16x32_f16(a[i], b[j], acc[i][j], 0, 0, 0);
    }
    const int rq = (lane >> 4) * 4;
    #pragma unroll
    for (int i = 0; i < 4; ++i)
        #pragma unroll
        for (int j = 0; j < 4; ++j)
            #pragma unroll
            for (int r = 0; r < 4; ++r)
                ctxW[(size_t)(m0 + i * 16 + rq + r) * HH + n0 + j * 16 + lm] =
                    (_Float16)acc[i][j][r];
}

// ---------------------------------------------------------------------------
// Grid barrier v4 (R5-proven): store-flag + all-poll, no RMW, no fence.
// ---------------------------------------------------------------------------
__device__ __forceinline__ void gbar4(unsigned* __restrict__ flags, unsigned round) {
    __syncthreads();  // drains all waves' bypass stores (vmcnt 0)
    const int tid = threadIdx.x;
    if (tid == 0) {
        asm volatile("s_waitcnt vmcnt(0)" ::: "memory");
        st_u32_coh(&flags[blockIdx.x], round);
    }
    if (tid < 64) {
        int guard = 0;
        for (;;) {
            const unsigned a0 = ld_u32_coh(&flags[tid * 4 + 0]);
            const unsigned a1 = ld_u32_coh(&flags[tid * 4 + 1]);
            const unsigned a2 = ld_u32_coh(&flags[tid * 4 + 2]);
            const unsigned a3 = ld_u32_coh(&flags[tid * 4 + 3]);
            if (a0 >= round && a1 >= round && a2 >= round && a3 >= round) break;
            __builtin_amdgcn_s_sleep(1);
            if (++guard > (1 << 20)) break;  // bail-out: wrong answer, not hang
        }
    }
    __syncthreads();
}

// ---------------------------------------------------------------------------
// Persistent kernel: whole 512-step scan in one launch.
// 256 blocks x 512 threads, 1 block/CU (~83KB LDS). 4 flag barriers/step.
// Step-invariant streams (block's ctxW slice for P2, ctx slice for P3) are
// PINNED IN REGISTERS once (128 VGPRs) -> 64 MB/step stream traffic removed.
// P4 re-partitioned per (b = bid>>3, colchunk = bid&7): colchunk is
// XCD-aligned so 32 blocks share a 512KB Wout16 slice in their XCD L2;
// activations (wc[b],hy[b]) are 4KB/block instead of 128KB.
// Cross-block RAW data: bypass stores + bypass loads (R5 semantics, no fence).
// ---------------------------------------------------------------------------
__global__ __launch_bounds__(512, 1) void k_persist(
    const _Float16* __restrict__ x16,     // [T*B, D]
    const _Float16* __restrict__ ctx_h,   // [S*B, H]
    const _Float16* __restrict__ ctxW,    // [S*B, H]
    const float* __restrict__ Whh,        // [4H, H] fp32
    const float* __restrict__ Wih,        // [4H, D] fp32
    const _Float16* __restrict__ Wout16,  // [H, 2H] fp16
    const float* __restrict__ bsum,       // [4H]
    const float* __restrict__ c0i,        // [B, H] initial c
    float* __restrict__ cbuf,             // [B, H] fp32 final c out
    _Float16* __restrict__ h16,           // [B, H] h carry
    _Float16* __restrict__ hy16,          // [B, H] cell output
    _Float16* __restrict__ wc16,          // [B, H] weighted context
    float* __restrict__ scores,           // [B, S]
    float* __restrict__ out,              // [T, B, H] fp32
    unsigned* __restrict__ bar) {
    __shared__ __align__(16) _Float16 sWHH[16 * 1024];  // 32KB
    __shared__ __align__(16) _Float16 sWIH[16 * 1024];  // 32KB
    __shared__ __align__(16) float sRED[4096];          // 16KB (also P4 A-staging)
    __shared__ float sSM[512];                          // 2KB
    __shared__ float sCB[128];                          // c carry (32b x 4col)

    const int bid = blockIdx.x;
    const int tid = threadIdx.x;
    const int w = tid >> 6, lane = tid & 63;
    const int lm = lane & 15, q8 = (lane >> 4) * 8;
    const int j0 = bid * 4;  // P1 column base (4 H-cols per block)

    // ---- one-time: stage P1 weight slices fp32->fp16 into LDS (XOR-swizzled) ----
    for (int idx = tid; idx < 16 * 128; idx += 512) {
        const int p = idx >> 7, k8 = idx & 127;
        const int g = (p >> 2) * HH + j0 + (p & 3);  // gate (p>>2), col j0+(p&3)
        const int dst = (p * 2048 + k8 * 16) ^ ((p & 7) << 4);
        *(f16x8*)((char*)sWHH + dst) = cvt8(Whh + (size_t)g * HH + k8 * 8);
        *(f16x8*)((char*)sWIH + dst) = cvt8(Wih + (size_t)g * DD + k8 * 8);
    }
    if (tid < 128) sCB[tid] = c0i[(size_t)(tid >> 2) * HH + j0 + (tid & 3)];
    __syncthreads();

    // ---- pin step-invariant stream slices in registers ----
    const int b2 = bid & 31, s02 = (bid >> 5) * 64;  // P2 partition
    f16x8 cw[16];
    #pragma unroll
    for (int i = 0; i < 8; ++i) {
        const _Float16* crow =
            ctxW + ((size_t)(s02 + w * 8 + i) * BB + b2) * HH + lane * 16;
        cw[2 * i] = *(const f16x8*)(crow);
        cw[2 * i + 1] = *(const f16x8*)(crow + 8);
    }
    const int b3 = bid >> 3, h03 = (bid & 7) * 128;  // P3 partition
    const int g3 = lane >> 4, c3 = lane & 15;        // P3 lane map
    f16x8 cx[16];
    {
        const _Float16* cb =
            ctx_h + ((size_t)(w * 64 + g3) * BB + b3) * HH + h03 + c3 * 8;
        #pragma unroll
        for (int i = 0; i < 16; ++i)
            cx[i] = *(const f16x8*)(cb + (size_t)(i * 4) * (BB * HH));
    }
    const int b4 = bid >> 3, jb4 = (bid & 7) * 128;  // P4 partition (XCD-aligned cc)
    const int rot = (bid & 7) * 32;                  // P1 k-rotation vs MALL line contention

    unsigned round = 0;
    for (int t = 0; t < TT; ++t) {
        // ================= P1: gates + LSTM cell =================
        {
            const int kb = (w & 3) * 256;
            f32x4 acc0 = (f32x4)0.0f, acc1 = (f32x4)0.0f;
            if (w < 4) {
                #pragma unroll
                for (int kk = 0; kk < 256; kk += 32) {
                    const int k0 = kb + ((kk + rot) & 255) + q8;
                    f16x8 a0 = ld16_coh(h16 + (size_t)lm * HH + k0);
                    f16x8 a1 = ld16_coh(h16 + (size_t)(16 + lm) * HH + k0);
                    f16x8 bb = *(const f16x8*)((const char*)sWHH +
                                 ((lm * 2048 + k0 * 2) ^ ((lm & 7) << 4)));
                    acc0 = __builtin_amdgcn_mfma_f32_16x16x32_f16(a0, bb, acc0, 0, 0, 0);
                    acc1 = __builtin_amdgcn_mfma_f32_16x16x32_f16(a1, bb, acc1, 0, 0, 0);
                }
            } else {
                const _Float16* Xb = x16 + (size_t)t * (BB * DD);
                #pragma unroll
                for (int kk = 0; kk < 256; kk += 32) {
                    const int k0 = kb + ((kk + rot) & 255) + q8;
                    f16x8 a0 = *(const f16x8*)(Xb + (size_t)lm * DD + k0);
                    f16x8 a1 = *(const f16x8*)(Xb + (size_t)(16 + lm) * DD + k0);
                    f16x8 bb = *(const f16x8*)((const char*)sWIH +
                                 ((lm * 2048 + k0 * 2) ^ ((lm & 7) << 4)));
                    acc0 = __builtin_amdgcn_mfma_f32_16x16x32_f16(a0, bb, acc0, 0, 0, 0);
                    acc1 = __builtin_amdgcn_mfma_f32_16x16x32_f16(a1, bb, acc1, 0, 0, 0);
                }
            }
            ((f32x4*)sRED)[(w * 2 + 0) * 64 + lane] = acc0;
            ((f32x4*)sRED)[(w * 2 + 1) * 64 + lane] = acc1;
            __syncthreads();
            {
                const int b = tid >> 4, p = tid & 15;
                const int mt = b >> 4, bi = b & 15;
                const int ln = ((bi >> 2) << 4) | p, r = bi & 3;
                float gv = 0.0f;
                #pragma unroll
                for (int w2 = 0; w2 < 8; ++w2)
                    gv += sRED[((w2 * 2 + mt) * 64 + ln) * 4 + r];
                sSM[tid] = gv;
            }
            __syncthreads();
            if (tid < 64) {
                const int b = tid >> 1, cp = (tid & 1) * 2;
                union { _Float16 h[2]; unsigned u; } pk;
                #pragma unroll
                for (int cc = 0; cc < 2; ++cc) {
                    const int c = cp + cc, j = j0 + c;
                    const float gi = sSM[b * 16 + 0 + c] + bsum[j];
                    const float gf = sSM[b * 16 + 4 + c] + bsum[HH + j];
                    const float gg = sSM[b * 16 + 8 + c] + bsum[2 * HH + j];
                    const float go = sSM[b * 16 + 12 + c] + bsum[3 * HH + j];
                    const float cprev = sCB[b * 4 + c];
                    const float cy = sigm(gf) * cprev + sigm(gi) * tanh_fast(gg);
                    const float hv = sigm(go) * tanh_fast(cy);
                    sCB[b * 4 + c] = cy;
                    pk.h[cc] = (_Float16)hv;
                }
                st_u32_coh((unsigned*)(hy16 + (size_t)b * HH + j0 + cp), pk.u);
            }
        }
        ++round;
        gbar4(bar, round);

        // ================= P2: scores from register-pinned ctxW =================
        {
            const _Float16* hrow = hy16 + (size_t)b2 * HH + lane * 16;
            const f16x8 hv0 = ld16_coh(hrow);
            const f16x8 hv1 = ld16_coh(hrow + 8);
            float hf[16];
            #pragma unroll
            for (int i = 0; i < 8; ++i) { hf[i] = (float)hv0[i]; hf[8 + i] = (float)hv1[i]; }
            #pragma unroll
            for (int i = 0; i < 8; ++i) {
                float sum = 0.0f;
                #pragma unroll
                for (int jj = 0; jj < 8; ++jj)
                    sum += hf[jj] * (float)cw[2 * i][jj] + hf[8 + jj] * (float)cw[2 * i + 1][jj];
                #pragma unroll
                for (int off = 32; off > 0; off >>= 1) sum += __shfl_down(sum, off, 64);
                if (lane == 0)
                    st_u32_coh((unsigned*)(scores + b2 * SS + s02 + w * 8 + i),
                               __float_as_uint(sum));
            }
        }
        ++round;
        gbar4(bar, round);

        // ============ P3: softmax + weighted context from register-pinned ctx ============
        {
            const float v =
                __uint_as_float(ld_u32_coh((const unsigned*)(scores + b3 * SS + tid)));
            float mx = v;
            #pragma unroll
            for (int off = 32; off > 0; off >>= 1) mx = fmaxf(mx, __shfl_xor(mx, off, 64));
            if (lane == 0) sRED[w] = mx;
            __syncthreads();
            mx = sRED[0];
            #pragma unroll
            for (int w2 = 1; w2 < 8; ++w2) mx = fmaxf(mx, sRED[w2]);
            const float e = __expf(v - mx);
            sSM[tid] = e;
            float ssum = e;
            #pragma unroll
            for (int off = 32; off > 0; off >>= 1) ssum += __shfl_xor(ssum, off, 64);
            if (lane == 0) sRED[8 + w] = ssum;
            __syncthreads();
            float tot = 0.0f;
            #pragma unroll
            for (int w2 = 0; w2 < 8; ++w2) tot += sRED[8 + w2];
            const float inv = 1.0f / tot;
            float acc[8];
            #pragma unroll
            for (int jj = 0; jj < 8; ++jj) acc[jj] = 0.0f;
            #pragma unroll
            for (int i = 0; i < 16; ++i) {
                const float aw = sSM[w * 64 + g3 + i * 4];
                #pragma unroll
                for (int jj = 0; jj < 8; ++jj) acc[jj] += aw * (float)cx[i][jj];
            }
            #pragma unroll
            for (int jj = 0; jj < 8; ++jj) {
                acc[jj] += __shfl_xor(acc[jj], 16, 64);
                acc[jj] += __shfl_xor(acc[jj], 32, 64);
            }
            __syncthreads();
            if (g3 == 0) {
                #pragma unroll
                for (int jj = 0; jj < 8; ++jj) sRED[w * 128 + c3 * 8 + jj] = acc[jj];
            }
            __syncthreads();
            if (tid < 64) {
                const int ccol = tid * 2;
                float sv0 = 0.0f, sv1 = 0.0f;
                #pragma unroll
                for (int w2 = 0; w2 < 8; ++w2) {
                    sv0 += sRED[w2 * 128 + ccol];
                    sv1 += sRED[w2 * 128 + ccol + 1];
                }
                union { _Float16 h[2]; unsigned u; } pk;
                pk.h[0] = (_Float16)(sv0 * inv);
                pk.h[1] = (_Float16)(sv1 * inv);
                st_u32_coh((unsigned*)(wc16 + (size_t)b3 * HH + h03 + ccol), pk.u);
            }
        }
        ++round;
        gbar4(bar, round);

        // ===== P4: h_tilde = tanh([wc,hy]@Wout^T), per-b partition, L2 weights =====
        {
            _Float16* sA = (_Float16*)sRED;  // 2048 fp16 = 4KB A-staging
            if (tid < 256)
                ((unsigned long long*)sA)[tid] =
                    ld_u64_coh((const unsigned long long*)(wc16 + (size_t)b4 * HH) + tid);
            else
                ((unsigned long long*)sA)[tid] =
                    ld_u64_coh((const unsigned long long*)(hy16 + (size_t)b4 * HH) +
                               (tid - 256));
            __syncthreads();
            const int jq = tid >> 2, q = tid & 3;
            const _Float16* wrow = Wout16 + (size_t)(jb4 + jq) * (2 * HH) + q * 512;
            const _Float16* arow = sA + q * 512;
            float sum = 0.0f;
            #pragma unroll 8
            for (int i = 0; i < 64; ++i) {
                const f16x8 wv = *(const f16x8*)(wrow + i * 8);
                const f16x8 av = *(const f16x8*)(arow + i * 8);
                #pragma unroll
                for (int jj = 0; jj < 8; ++jj) sum += (float)av[jj] * (float)wv[jj];
            }
            sum += __shfl_xor(sum, 1, 64);
            sum += __shfl_xor(sum, 2, 64);
            const float ht = tanh_fast(sum);
            if (q == 0)
                st_u32_coh(
                    (unsigned*)(out + (size_t)t * (BB * HH) + (size_t)b4 * HH + jb4 + jq),
                    __float_as_uint(ht));
            const float htn = __shfl(ht, (lane + 4) & 63, 64);
            if ((lane & 7) == 0) {
                union { _Float16 h[2]; unsigned u; } pk;
                pk.h[0] = (_Float16)ht;
                pk.h[1] = (_Float16)htn;
                st_u32_coh((unsigned*)(h16 + (size_t)b4 * HH + jb4 + jq), pk.u);
            }
        }
        ++round;
        gbar4(bar, round);
    }

    // final c carry -> global (bypass; k_fin's dispatch boundary sees MALL)
    if (tid < 128)
        st_u32_coh((unsigned*)&cbuf[(size_t)(tid >> 2) * HH + j0 + (tid & 3)],
                   __float_as_uint(sCB[tid]));
}

// ---------------------------------------------------------------------------
// OLD PATH kernels (fallback for small workspaces) -- unchanged
// ---------------------------------------------------------------------------
__global__ __launch_bounds__(64) void k_step1(const float* __restrict__ hprev,
                                              const _Float16* __restrict__ Whh_h,
                                              const float* __restrict__ Whh_f,
                                              const _Float16* __restrict__ gx_t,
                                              const float* __restrict__ xt_f,
                                              const _Float16* __restrict__ Wih_h,
                                              const float* __restrict__ Wih_f,
                                              const float* __restrict__ bsum,
                                              float* __restrict__ cbuf,
                                              float* __restrict__ hy,
                                              int use_pre, int staged) {
    const int wave = blockIdx.x;
    const int lane = threadIdx.x;
    const int m0 = (wave >> 6) * 16;
    const int j0 = (wave & 63) * 16;
    const int lm = lane & 15, q8 = (lane >> 4) * 8;

    f32x4 acc[4];
    #pragma unroll
    for (int q = 0; q < 4; ++q) acc[q] = (f32x4)0.0f;

    const float* arow = hprev + (size_t)(m0 + lm) * HH;
    if (staged) {
        for (int k0 = 0; k0 < HH; k0 += 32) {
            f16x8 a = cvt8(arow + k0 + q8);
            #pragma unroll
            for (int q = 0; q < 4; ++q) {
                f16x8 b = *(const f16x8*)(Whh_h + (size_t)(q * HH + j0 + lm) * HH + k0 + q8);
                acc[q] = __builtin_amdgcn_mfma_f32_16x16x32_f16(a, b, acc[q], 0, 0, 0);
            }
        }
    } else {
        for (int k0 = 0; k0 < HH; k0 += 32) {
            f16x8 a = cvt8(arow + k0 + q8);
            #pragma unroll
            for (int q = 0; q < 4; ++q) {
                f16x8 b = cvt8(Whh_f + (size_t)(q * HH + j0 + lm) * HH + k0 + q8);
                acc[q] = __builtin_amdgcn_mfma_f32_16x16x32_f16(a, b, acc[q], 0, 0, 0);
            }
        }
    }
    if (!use_pre) {
        const float* xrow = xt_f + (size_t)(m0 + lm) * DD;
        if (staged) {
            for (int k0 = 0; k0 < DD; k0 += 32) {
                f16x8 a = cvt8(xrow + k0 + q8);
                #pragma unroll
                for (int q = 0; q < 4; ++q) {
                    f16x8 b = *(const f16x8*)(Wih_h + (size_t)(q * HH + j0 + lm) * DD + k0 + q8);
                    acc[q] = __builtin_amdgcn_mfma_f32_16x16x32_f16(a, b, acc[q], 0, 0, 0);
                }
            }
        } else {
            for (int k0 = 0; k0 < DD; k0 += 32) {
                f16x8 a = cvt8(xrow + k0 + q8);
                #pragma unroll
                for (int q = 0; q < 4; ++q) {
                    f16x8 b = cvt8(Wih_f + (size_t)(q * HH + j0 + lm) * DD + k0 + q8);
                    acc[q] = __builtin_amdgcn_mfma_f32_16x16x32_f16(a, b, acc[q], 0, 0, 0);
                }
            }
        }
    }
    const int rq = (lane >> 4) * 4;
    const int j = j0 + lm;
    const float bs_i = bsum[j], bs_f = bsum[HH + j], bs_g = bsum[2 * HH + j], bs_o = bsum[3 * HH + j];
    #pragma unroll
    for (int r = 0; r < 4; ++r) {
        const int b = m0 + rq + r;
        float gi = acc[0][r] + bs_i, gf = acc[1][r] + bs_f;
        float gg = acc[2][r] + bs_g, go = acc[3][r] + bs_o;
        if (use_pre) {
            const _Float16* g = gx_t + (size_t)b * (4 * HH);
            gi += (float)g[j];
            gf += (float)g[HH + j];
            gg += (float)g[2 * HH + j];
            go += (float)g[3 * HH + j];
        }
        const float cprev = cbuf[b * HH + j];
        const float cy = sigm(gf) * cprev + sigm(gi) * tanh_fast(gg);
        const float hv = sigm(go) * tanh_fast(cy);
        cbuf[b * HH + j] = cy;
        hy[b * HH + j] = hv;
    }
}

__global__ __launch_bounds__(64) void k_target(const float* __restrict__ hy,
                                               const _Float16* __restrict__ Win_h,
                                               const float* __restrict__ Win_f,
                                               float* __restrict__ target,
                                               int staged) {
    const int wave = blockIdx.x;
    const int lane = threadIdx.x;
    const int m0 = (wave >> 6) * 16;
    const int j0 = (wave & 63) * 16;
    const int lm = lane & 15, q8 = (lane >> 4) * 8;

    f32x4 acc = (f32x4)0.0f;
    const float* arow = hy + (size_t)(m0 + lm) * HH;
    if (staged) {
        for (int k0 = 0; k0 < HH; k0 += 32) {
            f16x8 a = cvt8(arow + k0 + q8);
            f16x8 b = *(const f16x8*)(Win_h + (size_t)(j0 + lm) * HH + k0 + q8);
            acc = __builtin_amdgcn_mfma_f32_16x16x32_f16(a, b, acc, 0, 0, 0);
        }
    } else {
        for (int k0 = 0; k0 < HH; k0 += 32) {
            f16x8 a = cvt8(arow + k0 + q8);
            f16x8 b = cvt8(Win_f + (size_t)(j0 + lm) * HH + k0 + q8);
            acc = __builtin_amdgcn_mfma_f32_16x16x32_f16(a, b, acc, 0, 0, 0);
        }
    }
    const int rq = (lane >> 4) * 4;
    const int j = j0 + lm;
    #pragma unroll
    for (int r = 0; r < 4; ++r)
        target[(m0 + rq + r) * HH + j] = acc[r];
}

__global__ __launch_bounds__(256) void k_scores(const _Float16* __restrict__ ctx_h,
                                                const float* __restrict__ ctx_f,
                                                const float* __restrict__ target,
                                                float* __restrict__ scores, int staged) {
    const int idx = (blockIdx.x * blockDim.x + threadIdx.x) >> 6;  // b*512+s
    const int lane = threadIdx.x & 63;
    const int b = idx >> 9;
    const int s = idx & 511;
    const float* trow = target + b * HH + lane * 16;
    float4 t0 = *(const float4*)(trow);
    float4 t1 = *(const float4*)(trow + 4);
    float4 t2 = *(const float4*)(trow + 8);
    float4 t3 = *(const float4*)(trow + 12);
    float sum = 0.0f;
    if (staged) {
        const _Float16* crow = ctx_h + ((size_t)s * BB + b) * HH + lane * 16;
        f16x8 c0 = *(const f16x8*)(crow);
        f16x8 c1 = *(const f16x8*)(crow + 8);
        sum += (float)c0[0] * t0.x + (float)c0[1] * t0.y + (float)c0[2] * t0.z + (float)c0[3] * t0.w;
        sum += (float)c0[4] * t1.x + (float)c0[5] * t1.y + (float)c0[6] * t1.z + (float)c0[7] * t1.w;
        sum += (float)c1[0] * t2.x + (float)c1[1] * t2.y + (float)c1[2] * t2.z + (float)c1[3] * t2.w;
        sum += (float)c1[4] * t3.x + (float)c1[5] * t3.y + (float)c1[6] * t3.z + (float)c1[7] * t3.w;
    } else {
        const float* crow = ctx_f + ((size_t)s * BB + b) * HH + lane * 16;
        float4 c0 = *(const float4*)(crow);
        float4 c1 = *(const float4*)(crow + 4);
        float4 c2 = *(const float4*)(crow + 8);
        float4 c3 = *(const float4*)(crow + 12);
        sum += c0.x * t0.x + c0.y * t0.y + c0.z * t0.z + c0.w * t0.w;
        sum += c1.x * t1.x + c1.y * t1.y + c1.z * t1.z + c1.w * t1.w;
        sum += c2.x * t2.x + c2.y * t2.y + c2.z * t2.z + c2.w * t2.w;
        sum += c3.x * t3.x + c3.y * t3.y + c3.z * t3.z + c3.w * t3.w;
    }
    #pragma unroll
    for (int off = 32; off > 0; off >>= 1) sum += __shfl_down(sum, off, 64);
    if (lane == 0) scores[b * SS + s] = sum;
}

__global__ __launch_bounds__(256) void k_attn(const _Float16* __restrict__ ctx_h,
                                              const float* __restrict__ ctx_f,
                                              const float* __restrict__ scores,
                                              float* __restrict__ wc, int staged) {
    __shared__ float sm[SS];
    __shared__ float red[256];
    const int b = blockIdx.x >> 1;
    const int hc = blockIdx.x & 1;
    const int t = threadIdx.x;

    const float v0 = scores[b * SS + t];
    const float v1 = scores[b * SS + 256 + t];
    red[t] = fmaxf(v0, v1);
    __syncthreads();
    for (int o = 128; o > 0; o >>= 1) {
        if (t < o) red[t] = fmaxf(red[t], red[t + o]);
        __syncthreads();
    }
    const float mx = red[0];
    __syncthreads();
    const float e0 = __expf(v0 - mx);
    const float e1 = __expf(v1 - mx);
    sm[t] = e0;
    sm[t + 256] = e1;
    red[t] = e0 + e1;
    __syncthreads();
    for (int o = 128; o > 0; o >>= 1) {
        if (t < o) red[t] += red[t + o];
        __syncthreads();
    }
    const float inv = 1.0f / red[0];

    const int h = hc * 512 + t * 2;
    float a0 = 0.0f, a1 = 0.0f;
    if (staged) {
        const _Float16* cbase = ctx_h + (size_t)b * HH + h;
        #pragma unroll 8
        for (int s = 0; s < SS; ++s) {
            const float a = sm[s];
            const f16x2 u = *(const f16x2*)(cbase + (size_t)s * (BB * HH));
            a0 += a * (float)u[0];
            a1 += a * (float)u[1];
        }
    } else {
        const float* cbase = ctx_f + (size_t)b * HH + h;
        #pragma unroll 8
        for (int s = 0; s < SS; ++s) {
            const float a = sm[s];
            const float2 u = *(const float2*)(cbase + (size_t)s * (BB * HH));
            a0 += a * u.x;
            a1 += a * u.y;
        }
    }
    wc[b * HH + h] = a0 * inv;
    wc[b * HH + h + 1] = a1 * inv;
}

__global__ __launch_bounds__(64) void k_out(const float* __restrict__ wc,
                                            const float* __restrict__ hy,
                                            const _Float16* __restrict__ Wout_h,
                                            const float* __restrict__ Wout_f,
                                            float* __restrict__ out_t,
                                            int staged) {
    const int wave = blockIdx.x;
    const int lane = threadIdx.x;
    const int m0 = (wave >> 6) * 16;
    const int j0 = (wave & 63) * 16;
    const int lm = lane & 15, q8 = (lane >> 4) * 8;

    f32x4 acc = (f32x4)0.0f;
    const float* arow1 = wc + (size_t)(m0 + lm) * HH;
    const float* arow2 = hy + (size_t)(m0 + lm) * HH;
    if (staged) {
        const _Float16* brow = Wout_h + (size_t)(j0 + lm) * (2 * HH);
        for (int k0 = 0; k0 < HH; k0 += 32) {
            f16x8 a = cvt8(arow1 + k0 + q8);
            f16x8 b = *(const f16x8*)(brow + k0 + q8);
            acc = __builtin_amdgcn_mfma_f32_16x16x32_f16(a, b, acc, 0, 0, 0);
        }
        for (int k0 = 0; k0 < HH; k0 += 32) {
            f16x8 a = cvt8(arow2 + k0 + q8);
            f16x8 b = *(const f16x8*)(brow + HH + k0 + q8);
            acc = __builtin_amdgcn_mfma_f32_16x16x32_f16(a, b, acc, 0, 0, 0);
        }
    } else {
        const float* brow = Wout_f + (size_t)(j0 + lm) * (2 * HH);
        for (int k0 = 0; k0 < HH; k0 += 32) {
            f16x8 a = cvt8(arow1 + k0 + q8);
            f16x8 b = cvt8(brow + k0 + q8);
            acc = __builtin_amdgcn_mfma_f32_16x16x32_f16(a, b, acc, 0, 0, 0);
        }
        for (int k0 = 0; k0 < HH; k0 += 32) {
            f16x8 a = cvt8(arow2 + k0 + q8);
            f16x8 b = cvt8(brow + HH + k0 + q8);
            acc = __builtin_amdgcn_mfma_f32_16x16x32_f16(a, b, acc, 0, 0, 0);
        }
    }
    const int rq = (lane >> 4) * 4;
    const int j = j0 + lm;
    #pragma unroll
    for (int r = 0; r < 4; ++r)
        out_t[(m0 + rq + r) * HH + j] = tanh_fast(acc[r]);
}

// ---------------------------------------------------------------------------
// new-path workspace layout
// ---------------------------------------------------------------------------
static constexpr size_t NW_CBUF   = 0;          // 131072
static constexpr size_t NW_SCORES = 131072;     //  65536
static constexpr size_t NW_HY16   = 196608;     //  65536
static constexpr size_t NW_H16    = 262144;     //  65536
static constexpr size_t NW_WC16   = 327680;     //  65536
static constexpr size_t NW_BSUM   = 393216;     //  16384
static constexpr size_t NW_BAR    = 409600;     //   4096
static constexpr size_t NW_WINT   = 413696;     // 2097152
static constexpr size_t NW_X16    = 2510848;    // 33554432
static constexpr size_t NW_CTXH   = 36065280;   // 33554432
static constexpr size_t NW_CTXW   = 69619712;   // 33554432
static constexpr size_t NW_WOUT16 = 103174144;  //  4194304
static constexpr size_t NW_TOTAL  = 107368448;

extern "C" void kernel_launch(void* const* d_in, const int* in_sizes, int n_in,
                              void* d_out, int out_size, void* d_ws, size_t ws_size,
                              hipStream_t stream) {
    const float* x    = (const float*)d_in[0];
    const float* h0   = (const float*)d_in[1];
    const float* c0   = (const float*)d_in[2];
    const float* ctx  = (const float*)d_in[3];
    const float* Wih  = (const float*)d_in[4];
    const float* bih  = (const float*)d_in[5];
    const float* Whh  = (const float*)d_in[6];
    const float* bhh  = (const float*)d_in[7];
    const float* Win  = (const float*)d_in[8];
    const float* Wout = (const float*)d_in[9];
    float* out = (float*)d_out;
    char* ws = (char*)d_ws;

    if (ws_size >= NW_TOTAL) {
        // ---------------- persistent-kernel path ----------------
        float* cbuf       = (float*)(ws + NW_CBUF);
        float* scores     = (float*)(ws + NW_SCORES);
        _Float16* hy16    = (_Float16*)(ws + NW_HY16);
        _Float16* h16     = (_Float16*)(ws + NW_H16);
        _Float16* wc16    = (_Float16*)(ws + NW_WC16);
        float* bsum       = (float*)(ws + NW_BSUM);
        unsigned* bar     = (unsigned*)(ws + NW_BAR);
        _Float16* WinT    = (_Float16*)(ws + NW_WINT);
        _Float16* x16     = (_Float16*)(ws + NW_X16);
        _Float16* ctx_h   = (_Float16*)(ws + NW_CTXH);
        _Float16* ctxW    = (_Float16*)(ws + NW_CTXW);
        _Float16* Wout16  = (_Float16*)(ws + NW_WOUT16);

        k_bias<<<16, 256, 0, stream>>>(bih, bhh, bsum);
        k_zero<<<4, 256, 0, stream>>>(bar);
        k_cvt<<<2048, 256, 0, stream>>>(ctx, ctx_h, SS * BB * HH / 4);
        k_cvt<<<4096, 256, 0, stream>>>(x, x16, TT * BB * DD / 4);
        k_cvt<<<32, 256, 0, stream>>>(h0, h16, BB * HH / 4);
        k_cvt<<<512, 256, 0, stream>>>(Wout, Wout16, HH * 2 * HH / 4);
        k_trwin<<<1024, 256, 0, stream>>>(Win, WinT);
        k_ctxw<<<1024, 256, 0, stream>>>(ctx, WinT, ctxW);

        k_persist<<<256, 512, 0, stream>>>(x16, ctx_h, ctxW, Whh, Wih, Wout16, bsum,
                                           c0, cbuf, h16, hy16, wc16, scores, out, bar);

        float* hT = out + (size_t)TT * BB * HH;
        float* cT = hT + BB * HH;
        k_fin<<<128, 256, 0, stream>>>(out + (size_t)(TT - 1) * BB * HH, cbuf, hT, cT);
        return;
    }

    // ---------------- old path (fallback, unchanged) ----------------
    float* cbuf   = (float*)(ws + 0);        // 131072
    float* hy     = (float*)(ws + 131072);   // 131072
    float* target = (float*)(ws + 262144);   // 131072
    float* scores = (float*)(ws + 393216);   //  65536
    float* wc     = (float*)(ws + 458752);   // 131072
    float* bsum   = (float*)(ws + 589824);   //  16384
    _Float16* Whh_h  = (_Float16*)(ws + 606208);    //  8388608
    _Float16* Win_h  = (_Float16*)(ws + 8994816);   //  2097152
    _Float16* Wout_h = (_Float16*)(ws + 11091968);  //  4194304
    _Float16* Wih_h  = (_Float16*)(ws + 15286272);  //  8388608
    _Float16* ctx_h  = (_Float16*)(ws + 23674880);  // 33554432
    _Float16* gx     = (_Float16*)(ws + 57229312);  // 134217728

    const int staged  = (ws_size >= (size_t)57229312) ? 1 : 0;
    const int use_pre = (ws_size >= (size_t)191447040) ? 1 : 0;

    k_bias<<<16, 256, 0, stream>>>(bih, bhh, bsum);
    k_init<<<128, 256, 0, stream>>>(c0, cbuf);
    if (staged) {
        k_cvt<<<1024, 256, 0, stream>>>(Whh, Whh_h, 4 * HH * HH / 4);
        k_cvt<<<1024, 256, 0, stream>>>(Win, Win_h, HH * HH / 4);
        k_cvt<<<1024, 256, 0, stream>>>(Wout, Wout_h, 2 * HH * HH / 4);
        k_cvt<<<2048, 256, 0, stream>>>(ctx, ctx_h, SS * BB * HH / 4);
        if (!use_pre) k_cvt<<<1024, 256, 0, stream>>>(Wih, Wih_h, 4 * HH * DD / 4);
    }
    if (use_pre) k_pre<<<4096, 256, 0, stream>>>(x, Wih, gx);

    for (int t = 0; t < TT; ++t) {
        const float* hprev = (t == 0) ? h0 : (out + (size_t)(t - 1) * BB * HH);
        const _Float16* gx_t = gx + (size_t)t * BB * 4 * HH;
        const float* xt = x + (size_t)t * BB * DD;
        float* out_t = out + (size_t)t * BB * HH;

        k_step1<<<128, 64, 0, stream>>>(hprev, Whh_h, Whh, gx_t, xt, Wih_h, Wih,
                                        bsum, cbuf, hy, use_pre, staged);
        k_target<<<128, 64, 0, stream>>>(hy, Win_h, Win, target, staged);
        k_scores<<<4096, 256, 0, stream>>>(ctx_h, ctx, target, scores, staged);
        k_attn<<<64, 256, 0, stream>>>(ctx_h, ctx, scores, wc, staged);
        k_out<<<128, 64, 0, stream>>>(wc, hy, Wout_h, Wout, out_t, staged);
    }

    float* hT = out + (size_t)TT * BB * HH;
    float* cT = hT + BB * HH;
    k_fin<<<128, 256, 0, stream>>>(out + (size_t)(TT - 1) * BB * HH, cbuf, hT, cT);
}

// Round 8
// 24881.639 us; speedup vs baseline: 1.6634x; 1.6634x over previous
//
#include <hip/hip_runtime.h>
#include <hip/hip_bf16.h>
#include <cstdint>
#include <cstddef>

// Problem constants
#define TT 512
#define BB 32
#define DD 1024
#define HH 1024
#define SS 512

typedef _Float16 f16x8 __attribute__((ext_vector_type(8)));
typedef _Float16 f16x4 __attribute__((ext_vector_type(4)));
typedef _Float16 f16x2 __attribute__((ext_vector_type(2)));
typedef float f32x4 __attribute__((ext_vector_type(4)));

__device__ __forceinline__ float sigm(float x) { return 1.0f / (1.0f + __expf(-x)); }
__device__ __forceinline__ float tanh_fast(float x) {
    return 1.0f - 2.0f / (__expf(2.0f * x) + 1.0f);  // saturates, no inf/inf
}
// load 8 contiguous fp32, round to fp16 MFMA fragment
__device__ __forceinline__ f16x8 cvt8(const float* __restrict__ p) {
    float4 u = *(const float4*)p;
    float4 v = *(const float4*)(p + 4);
    f16x8 r;
    r[0] = (_Float16)u.x; r[1] = (_Float16)u.y; r[2] = (_Float16)u.z; r[3] = (_Float16)u.w;
    r[4] = (_Float16)v.x; r[5] = (_Float16)v.y; r[6] = (_Float16)v.z; r[7] = (_Float16)v.w;
    return r;
}

// ---------------------------------------------------------------------------
// Cache-bypassing (coherent-point) access helpers for cross-block RAW data.
// Relaxed agent-scope atomics bypass per-XCD L1/L2 (and MALL allocation) —
// measured behavior: they are served from HBM, ~900cy latency. Use only for
// small RAW tensors, and in BURST form (many independent loads in flight).
// ---------------------------------------------------------------------------
__device__ __forceinline__ void st_u32_coh(unsigned* p, unsigned v) {
    __hip_atomic_store(p, v, __ATOMIC_RELAXED, __HIP_MEMORY_SCOPE_AGENT);
}
__device__ __forceinline__ unsigned ld_u32_coh(const unsigned* p) {
    return __hip_atomic_load(p, __ATOMIC_RELAXED, __HIP_MEMORY_SCOPE_AGENT);
}
__device__ __forceinline__ unsigned long long ld_u64_coh(const unsigned long long* p) {
    return __hip_atomic_load(p, __ATOMIC_RELAXED, __HIP_MEMORY_SCOPE_AGENT);
}
__device__ __forceinline__ f16x8 ld16_coh(const _Float16* p) {
    union { unsigned long long q[2]; f16x8 h; } u;
    u.q[0] = ld_u64_coh((const unsigned long long*)p);
    u.q[1] = ld_u64_coh((const unsigned long long*)p + 1);
    return u.h;
}

// ---------------------------------------------------------------------------
// staging: fp32 -> fp16 copy (grid-stride, float4 -> f16x4)
// ---------------------------------------------------------------------------
__global__ __launch_bounds__(256) void k_cvt(const float* __restrict__ s,
                                             _Float16* __restrict__ d, int n4) {
    for (int i = blockIdx.x * blockDim.x + threadIdx.x; i < n4; i += gridDim.x * blockDim.x) {
        float4 v = ((const float4*)s)[i];
        f16x4 h;
        h[0] = (_Float16)v.x; h[1] = (_Float16)v.y;
        h[2] = (_Float16)v.z; h[3] = (_Float16)v.w;
        ((f16x4*)d)[i] = h;
    }
}

__global__ void k_bias(const float* __restrict__ bih, const float* __restrict__ bhh,
                       float* __restrict__ bsum) {
    const int i = blockIdx.x * blockDim.x + threadIdx.x;
    if (i < 4 * HH) bsum[i] = bih[i] + bhh[i];
}

__global__ void k_init(const float* __restrict__ c0, float* __restrict__ cbuf) {
    const int i = blockIdx.x * blockDim.x + threadIdx.x;
    if (i < BB * HH) cbuf[i] = c0[i];
}

// zero the WHOLE barrier region (stale values from a previous graph replay
// would make every barrier fall through).
__global__ void k_zero(unsigned* __restrict__ p) {
    const int i = blockIdx.x * blockDim.x + threadIdx.x;
    if (i < 1024) p[i] = 0u;
}

__global__ void k_fin(const float* __restrict__ lasth, const float* __restrict__ cbuf,
                      float* __restrict__ hT, float* __restrict__ cT) {
    const int i = blockIdx.x * blockDim.x + threadIdx.x;
    if (i < BB * HH) {
        hT[i] = lasth[i];
        cT[i] = cbuf[i];
    }
}

// ---------------------------------------------------------------------------
// K_pre (old path only)
// ---------------------------------------------------------------------------
__global__ __launch_bounds__(256) void k_pre(const float* __restrict__ x,
                                             const float* __restrict__ Wih,
                                             _Float16* __restrict__ gx) {
    const int wave = (blockIdx.x * blockDim.x + threadIdx.x) >> 6;
    const int lane = threadIdx.x & 63;
    const int m0 = (wave >> 6) * 64, n0 = (wave & 63) * 64;
    const int lm = lane & 15, q8 = (lane >> 4) * 8;

    f32x4 acc[4][4];
    #pragma unroll
    for (int i = 0; i < 4; ++i)
        #pragma unroll
        for (int j = 0; j < 4; ++j) acc[i][j] = (f32x4)0.0f;

    for (int k0 = 0; k0 < DD; k0 += 32) {
        f16x8 a[4], b[4];
        #pragma unroll
        for (int i = 0; i < 4; ++i)
            a[i] = cvt8(x + (size_t)(m0 + i * 16 + lm) * DD + k0 + q8);
        #pragma unroll
        for (int j = 0; j < 4; ++j)
            b[j] = cvt8(Wih + (size_t)(n0 + j * 16 + lm) * DD + k0 + q8);
        #pragma unroll
        for (int i = 0; i < 4; ++i)
            #pragma unroll
            for (int j = 0; j < 4; ++j)
                acc[i][j] = __builtin_amdgcn_mfma_f32_16x16x32_f16(a[i], b[j], acc[i][j], 0, 0, 0);
    }
    const int rq = (lane >> 4) * 4;
    #pragma unroll
    for (int i = 0; i < 4; ++i)
        #pragma unroll
        for (int j = 0; j < 4; ++j)
            #pragma unroll
            for (int r = 0; r < 4; ++r)
                gx[(size_t)(m0 + i * 16 + rq + r) * (4 * HH) + n0 + j * 16 + lm] =
                    (_Float16)acc[i][j][r];
}

// ---------------------------------------------------------------------------
// k_trwin: WinT[k][j] = Win[j][k] as fp16 (one-time, for ctxW GEMM)
// ---------------------------------------------------------------------------
__global__ __launch_bounds__(256) void k_trwin(const float* __restrict__ Win,
                                               _Float16* __restrict__ WinT) {
    __shared__ float tile[32][33];
    const int bx = blockIdx.x & 31, by = blockIdx.x >> 5;
    const int tx = threadIdx.x & 31, ty = threadIdx.x >> 5;
    #pragma unroll
    for (int r = 0; r < 4; ++r)
        tile[ty + r * 8][tx] = Win[(size_t)(by * 32 + ty + r * 8) * HH + bx * 32 + tx];
    __syncthreads();
    #pragma unroll
    for (int r = 0; r < 4; ++r)
        WinT[(size_t)(bx * 32 + ty + r * 8) * HH + by * 32 + tx] =
            (_Float16)tile[tx][ty + r * 8];
}

// ---------------------------------------------------------------------------
// k_ctxw: ctxW[(s,b),k] = sum_j ctx[(s,b),j] * WinT[k,j]  (= ctx @ Win)
// ---------------------------------------------------------------------------
__global__ __launch_bounds__(256) void k_ctxw(const float* __restrict__ ctxf,
                                              const _Float16* __restrict__ WinT,
                                              _Float16* __restrict__ ctxW) {
    const int wave = (blockIdx.x * blockDim.x + threadIdx.x) >> 6;  // 4096 waves
    const int lane = threadIdx.x & 63;
    const int m0 = (wave >> 4) * 64, n0 = (wave & 15) * 64;
    const int lm = lane & 15, q8 = (lane >> 4) * 8;

    f32x4 acc[4][4];
    #pragma unroll
    for (int i = 0; i < 4; ++i)
        #pragma unroll
        for (int j = 0; j < 4; ++j) acc[i][j] = (f32x4)0.0f;

    for (int k0 = 0; k0 < HH; k0 += 32) {
        f16x8 a[4], b[4];
        #pragma unroll
        for (int i = 0; i < 4; ++i)
            a[i] = cvt8(ctxf + (size_t)(m0 + i * 16 + lm) * HH + k0 + q8);
        #pragma unroll
        for (int j = 0; j < 4; ++j)
            b[j] = *(const f16x8*)(WinT + (size_t)(n0 + j * 16 + lm) * HH + k0 + q8);
        #pragma unroll
        for (int i = 0; i < 4; ++i)
            #pragma unroll
            for (int j = 0; j < 4; ++j)
                acc[i][j] = __builtin_amdgcn_mfma_f32_16x16x32_f16(a[i], b[j], acc[i][j], 0, 0, 0);
    }
    const int rq = (lane >> 4) * 4;
    #pragma unroll
    for (int i = 0; i < 4; ++i)
        #pragma unroll
        for (int j = 0; j < 4; ++j)
            #pragma unroll
            for (int r = 0; r < 4; ++r)
                ctxW[(size_t)(m0 + i * 16 + rq + r) * HH + n0 + j * 16 + lm] =
                    (_Float16)acc[i][j][r];
}

// ---------------------------------------------------------------------------
// Grid barrier v4 (R5-proven): store-flag + all-poll, no RMW, no fence.
// ---------------------------------------------------------------------------
__device__ __forceinline__ void gbar4(unsigned* __restrict__ flags, unsigned round) {
    __syncthreads();  // drains all waves' bypass stores (vmcnt 0)
    const int tid = threadIdx.x;
    if (tid == 0) {
        asm volatile("s_waitcnt vmcnt(0)" ::: "memory");
        st_u32_coh(&flags[blockIdx.x], round);
    }
    if (tid < 64) {
        int guard = 0;
        for (;;) {
            const unsigned a0 = ld_u32_coh(&flags[tid * 4 + 0]);
            const unsigned a1 = ld_u32_coh(&flags[tid * 4 + 1]);
            const unsigned a2 = ld_u32_coh(&flags[tid * 4 + 2]);
            const unsigned a3 = ld_u32_coh(&flags[tid * 4 + 3]);
            if (a0 >= round && a1 >= round && a2 >= round && a3 >= round) break;
            __builtin_amdgcn_s_sleep(1);
            if (++guard > (1 << 20)) break;  // bail-out: wrong answer, not hang
        }
    }
    __syncthreads();
}

// ---------------------------------------------------------------------------
// Persistent kernel: whole 512-step scan in one launch.
// 256 blocks x 512 threads, 1 block/CU (~155KB LDS). 4 flag barriers/step.
// KEY (R8): the cross-block gathers (h16 in P1; wc16/hy16 in P4) are BURST
// COPIES into an XOR-swizzled LDS tile sH[32][1024] — each thread issues 8
// independent 16B bypass loads (whole 64KB in flight per block), converting
// ~900cy-latency-bound interleaved reads into HBM-bandwidth-bound bursts.
// MFMA A-fragments then come from LDS. P2/P3 stream read-only ctxW/ctx via
// normal cached loads. Cross-block RAW: bypass stores + bypass loads.
// ---------------------------------------------------------------------------
__global__ __launch_bounds__(512, 1) void k_persist(
    const _Float16* __restrict__ x16,    // [T*B, D]
    const _Float16* __restrict__ ctx_h,  // [S*B, H]
    const _Float16* __restrict__ ctxW,   // [S*B, H]
    const float* __restrict__ Whh,       // [4H, H] fp32
    const float* __restrict__ Wih,       // [4H, D] fp32
    const float* __restrict__ Wout,      // [H, 2H] fp32
    const float* __restrict__ bsum,      // [4H]
    const float* __restrict__ c0i,       // [B, H] initial c
    float* __restrict__ cbuf,            // [B, H] fp32 final c out
    _Float16* __restrict__ h16,          // [B, H] h carry
    _Float16* __restrict__ hy16,         // [B, H] cell output
    _Float16* __restrict__ wc16,         // [B, H] weighted context
    float* __restrict__ scores,          // [B, S]
    float* __restrict__ out,             // [T, B, H] fp32
    unsigned* __restrict__ bar) {
    __shared__ __align__(16) _Float16 sWHH[16 * 1024];  // 32KB (P1 Whh slice)
    __shared__ __align__(16) _Float16 sWIH[16 * 1024];  // 32KB (P1 Wih slice)
    __shared__ __align__(16) _Float16 sWOUT[4 * 2048];  // 16KB (P4 Wout slice)
    __shared__ __align__(16) _Float16 sH[32 * 1024];    // 64KB burst-gather tile
    __shared__ __align__(16) float sRED[2048];          // 8KB (two-stage reduces)
    __shared__ float sSM[512];                          // 2KB
    __shared__ float sCB[128];                          // c carry (32b x 4col)

    const int bid = blockIdx.x;
    const int tid = threadIdx.x;
    const int w = tid >> 6, lane = tid & 63;
    const int lm = lane & 15, q8 = (lane >> 4) * 8;
    const int j0 = bid * 4;  // P1/P4 column base (4 H-cols per block)

    // ---- one-time: stage weight slices fp32->fp16 into LDS (XOR-swizzled) ----
    for (int idx = tid; idx < 16 * 128; idx += 512) {
        const int p = idx >> 7, k8 = idx & 127;
        const int g = (p >> 2) * HH + j0 + (p & 3);  // gate (p>>2), col j0+(p&3)
        const int dst = (p * 2048 + k8 * 16) ^ ((p & 7) << 4);
        *(f16x8*)((char*)sWHH + dst) = cvt8(Whh + (size_t)g * HH + k8 * 8);
        *(f16x8*)((char*)sWIH + dst) = cvt8(Wih + (size_t)g * DD + k8 * 8);
    }
    for (int idx = tid; idx < 4 * 256; idx += 512) {
        const int p = idx >> 8, k8 = idx & 255;  // p = output col 0..3
        *(f16x8*)((char*)sWOUT + ((p * 4096 + k8 * 16) ^ (p << 4))) =
            cvt8(Wout + (size_t)(j0 + p) * (2 * HH) + k8 * 8);
    }
    if (tid < 128) sCB[tid] = c0i[(size_t)(tid >> 2) * HH + j0 + (tid & 3)];
    __syncthreads();

    unsigned round = 0;
    for (int t = 0; t < TT; ++t) {
        // ================= P1: gates + LSTM cell =================
        {
            // burst copy h16 -> sH (swizzled rows), all 64KB in flight
            #pragma unroll
            for (int u = 0; u < 8; ++u) {
                const int idx = u * 512 + tid;  // 0..4095
                const int row = idx >> 7, c16 = idx & 127;
                const f16x8 v = ld16_coh(h16 + (size_t)row * HH + c16 * 8);
                *(f16x8*)((char*)sH + ((row * 2048 + c16 * 16) ^ ((row & 7) << 4))) = v;
            }
            __syncthreads();
            const int kb = (w & 3) * 256;
            f32x4 acc0 = (f32x4)0.0f, acc1 = (f32x4)0.0f;
            if (w < 4) {
                #pragma unroll
                for (int kk = 0; kk < 256; kk += 32) {
                    const int k0 = kb + kk + q8;
                    f16x8 a0 = *(const f16x8*)((const char*)sH +
                                 ((lm * 2048 + k0 * 2) ^ ((lm & 7) << 4)));
                    f16x8 a1 = *(const f16x8*)((const char*)sH +
                                 (((16 + lm) * 2048 + k0 * 2) ^ ((lm & 7) << 4)));
                    f16x8 bb = *(const f16x8*)((const char*)sWHH +
                                 ((lm * 2048 + k0 * 2) ^ ((lm & 7) << 4)));
                    acc0 = __builtin_amdgcn_mfma_f32_16x16x32_f16(a0, bb, acc0, 0, 0, 0);
                    acc1 = __builtin_amdgcn_mfma_f32_16x16x32_f16(a1, bb, acc1, 0, 0, 0);
                }
            } else {
                const _Float16* Xb = x16 + (size_t)t * (BB * DD);
                #pragma unroll
                for (int kk = 0; kk < 256; kk += 32) {
                    const int k0 = kb + kk + q8;
                    f16x8 a0 = *(const f16x8*)(Xb + (size_t)lm * DD + k0);
                    f16x8 a1 = *(const f16x8*)(Xb + (size_t)(16 + lm) * DD + k0);
                    f16x8 bb = *(const f16x8*)((const char*)sWIH +
                                 ((lm * 2048 + k0 * 2) ^ ((lm & 7) << 4)));
                    acc0 = __builtin_amdgcn_mfma_f32_16x16x32_f16(a0, bb, acc0, 0, 0, 0);
                    acc1 = __builtin_amdgcn_mfma_f32_16x16x32_f16(a1, bb, acc1, 0, 0, 0);
                }
            }
            // two-stage reduce (fits 8KB sRED)
            ((f32x4*)sRED)[w * 64 + lane] = acc0;
            __syncthreads();
            if (tid < 256) {  // batches 0..15 (acc0)
                const int b = tid >> 4, p = tid & 15;
                const int bi = b & 15;
                const int ln = ((bi >> 2) << 4) | p, r = bi & 3;
                float gv = 0.0f;
                #pragma unroll
                for (int w2 = 0; w2 < 8; ++w2) gv += sRED[(w2 * 64 + ln) * 4 + r];
                sSM[tid] = gv;
            }
            __syncthreads();
            ((f32x4*)sRED)[w * 64 + lane] = acc1;
            __syncthreads();
            if (tid >= 256) {  // batches 16..31 (acc1)
                const int b = tid >> 4, p = tid & 15;
                const int bi = b & 15;
                const int ln = ((bi >> 2) << 4) | p, r = bi & 3;
                float gv = 0.0f;
                #pragma unroll
                for (int w2 = 0; w2 < 8; ++w2) gv += sRED[(w2 * 64 + ln) * 4 + r];
                sSM[tid] = gv;
            }
            __syncthreads();
            if (tid < 64) {
                const int b = tid >> 1, cp = (tid & 1) * 2;
                union { _Float16 h[2]; unsigned u; } pk;
                #pragma unroll
                for (int cc = 0; cc < 2; ++cc) {
                    const int c = cp + cc, j = j0 + c;
                    const float gi = sSM[b * 16 + 0 + c] + bsum[j];
                    const float gf = sSM[b * 16 + 4 + c] + bsum[HH + j];
                    const float gg = sSM[b * 16 + 8 + c] + bsum[2 * HH + j];
                    const float go = sSM[b * 16 + 12 + c] + bsum[3 * HH + j];
                    const float cprev = sCB[b * 4 + c];
                    const float cy = sigm(gf) * cprev + sigm(gi) * tanh_fast(gg);
                    const float hv = sigm(go) * tanh_fast(cy);
                    sCB[b * 4 + c] = cy;
                    pk.h[cc] = (_Float16)hv;
                }
                st_u32_coh((unsigned*)(hy16 + (size_t)b * HH + j0 + cp), pk.u);
            }
        }
        ++round;
        gbar4(bar, round);

        // ================= P2: scores via cached ctxW stream =================
        {
            const int b = bid & 31, s0 = (bid >> 5) * 64;
            const _Float16* hrow = hy16 + (size_t)b * HH + lane * 16;
            const f16x8 hv0 = ld16_coh(hrow);
            const f16x8 hv1 = ld16_coh(hrow + 8);
            float hf[16];
            #pragma unroll
            for (int i = 0; i < 8; ++i) { hf[i] = (float)hv0[i]; hf[8 + i] = (float)hv1[i]; }
            f16x8 cr0[8], cr1[8];
            #pragma unroll
            for (int i = 0; i < 8; ++i) {
                const _Float16* crow =
                    ctxW + ((size_t)(s0 + w * 8 + i) * BB + b) * HH + lane * 16;
                cr0[i] = *(const f16x8*)(crow);
                cr1[i] = *(const f16x8*)(crow + 8);
            }
            #pragma unroll
            for (int i = 0; i < 8; ++i) {
                float sum = 0.0f;
                #pragma unroll
                for (int jj = 0; jj < 8; ++jj)
                    sum += hf[jj] * (float)cr0[i][jj] + hf[8 + jj] * (float)cr1[i][jj];
                #pragma unroll
                for (int off = 32; off > 0; off >>= 1) sum += __shfl_down(sum, off, 64);
                if (lane == 0)
                    st_u32_coh((unsigned*)(scores + b * SS + s0 + w * 8 + i),
                               __float_as_uint(sum));
            }
        }
        ++round;
        gbar4(bar, round);

        // ========= P3: softmax + weighted context (cached ctx, 16B loads) =========
        {
            const int b = bid >> 3, h0 = (bid & 7) * 128;
            const float v =
                __uint_as_float(ld_u32_coh((const unsigned*)(scores + b * SS + tid)));
            float mx = v;
            #pragma unroll
            for (int off = 32; off > 0; off >>= 1) mx = fmaxf(mx, __shfl_xor(mx, off, 64));
            if (lane == 0) sRED[w] = mx;
            __syncthreads();
            mx = sRED[0];
            #pragma unroll
            for (int w2 = 1; w2 < 8; ++w2) mx = fmaxf(mx, sRED[w2]);
            const float e = __expf(v - mx);
            sSM[tid] = e;
            float ssum = e;
            #pragma unroll
            for (int off = 32; off > 0; off >>= 1) ssum += __shfl_xor(ssum, off, 64);
            if (lane == 0) sRED[8 + w] = ssum;
            __syncthreads();
            float tot = 0.0f;
            #pragma unroll
            for (int w2 = 0; w2 < 8; ++w2) tot += sRED[8 + w2];
            const float inv = 1.0f / tot;
            // wave w covers s in [w*64, w*64+64); lane = (g = s-subgroup, c = 8-col grp)
            const int g = lane >> 4, c = lane & 15;
            float acc[8];
            #pragma unroll
            for (int jj = 0; jj < 8; ++jj) acc[jj] = 0.0f;
            const _Float16* cb =
                ctx_h + ((size_t)(w * 64 + g) * BB + b) * HH + h0 + c * 8;
            #pragma unroll
            for (int i = 0; i < 16; ++i) {
                const float aw = sSM[w * 64 + g + i * 4];
                const f16x8 u = *(const f16x8*)(cb + (size_t)(i * 4) * (BB * HH));
                #pragma unroll
                for (int jj = 0; jj < 8; ++jj) acc[jj] += aw * (float)u[jj];
            }
            #pragma unroll
            for (int jj = 0; jj < 8; ++jj) {
                acc[jj] += __shfl_xor(acc[jj], 16, 64);
                acc[jj] += __shfl_xor(acc[jj], 32, 64);
            }
            __syncthreads();
            if (g == 0) {
                #pragma unroll
                for (int jj = 0; jj < 8; ++jj) sRED[w * 128 + c * 8 + jj] = acc[jj];
            }
            __syncthreads();
            if (tid < 64) {
                const int ccol = tid * 2;
                float sv0 = 0.0f, sv1 = 0.0f;
                #pragma unroll
                for (int w2 = 0; w2 < 8; ++w2) {
                    sv0 += sRED[w2 * 128 + ccol];
                    sv1 += sRED[w2 * 128 + ccol + 1];
                }
                union { _Float16 h[2]; unsigned u; } pk;
                pk.h[0] = (_Float16)(sv0 * inv);
                pk.h[1] = (_Float16)(sv1 * inv);
                st_u32_coh((unsigned*)(wc16 + (size_t)b * HH + h0 + ccol), pk.u);
            }
        }
        ++round;
        gbar4(bar, round);

        // ===== P4: h_tilde = tanh([wc,hy]@Wout^T), burst-gather sub-phases =====
        {
            const int pc = lm & 3;  // replicated output col 0..3
            const int kb = w * 128;
            f32x4 acc0 = (f32x4)0.0f, acc1 = (f32x4)0.0f;
            // sub-phase A: wc
            #pragma unroll
            for (int u = 0; u < 8; ++u) {
                const int idx = u * 512 + tid;
                const int row = idx >> 7, c16 = idx & 127;
                const f16x8 v = ld16_coh(wc16 + (size_t)row * HH + c16 * 8);
                *(f16x8*)((char*)sH + ((row * 2048 + c16 * 16) ^ ((row & 7) << 4))) = v;
            }
            __syncthreads();
            #pragma unroll
            for (int kk = 0; kk < 128; kk += 32) {
                const int k0 = kb + kk + q8;
                f16x8 a0 = *(const f16x8*)((const char*)sH +
                             ((lm * 2048 + k0 * 2) ^ ((lm & 7) << 4)));
                f16x8 a1 = *(const f16x8*)((const char*)sH +
                             (((16 + lm) * 2048 + k0 * 2) ^ ((lm & 7) << 4)));
                f16x8 bb = *(const f16x8*)((const char*)sWOUT +
                             ((pc * 4096 + k0 * 2) ^ (pc << 4)));
                acc0 = __builtin_amdgcn_mfma_f32_16x16x32_f16(a0, bb, acc0, 0, 0, 0);
                acc1 = __builtin_amdgcn_mfma_f32_16x16x32_f16(a1, bb, acc1, 0, 0, 0);
            }
            __syncthreads();  // all waves done reading sH before overwrite
            // sub-phase B: hy
            #pragma unroll
            for (int u = 0; u < 8; ++u) {
                const int idx = u * 512 + tid;
                const int row = idx >> 7, c16 = idx & 127;
                const f16x8 v = ld16_coh(hy16 + (size_t)row * HH + c16 * 8);
                *(f16x8*)((char*)sH + ((row * 2048 + c16 * 16) ^ ((row & 7) << 4))) = v;
            }
            __syncthreads();
            #pragma unroll
            for (int kk = 0; kk < 128; kk += 32) {
                const int k0 = kb + kk + q8;
                f16x8 a0 = *(const f16x8*)((const char*)sH +
                             ((lm * 2048 + k0 * 2) ^ ((lm & 7) << 4)));
                f16x8 a1 = *(const f16x8*)((const char*)sH +
                             (((16 + lm) * 2048 + k0 * 2) ^ ((lm & 7) << 4)));
                f16x8 bb = *(const f16x8*)((const char*)sWOUT +
                             ((pc * 4096 + (HH + k0) * 2) ^ (pc << 4)));
                acc0 = __builtin_amdgcn_mfma_f32_16x16x32_f16(a0, bb, acc0, 0, 0, 0);
                acc1 = __builtin_amdgcn_mfma_f32_16x16x32_f16(a1, bb, acc1, 0, 0, 0);
            }
            // two-stage reduce + epilogue
            ((f32x4*)sRED)[w * 64 + lane] = acc0;
            __syncthreads();
            if (tid < 256) {  // batches 0..15
                const int b = tid >> 4, p = tid & 15;
                const int bi = b & 15;
                const int ln = ((bi >> 2) << 4) | p, r = bi & 3;
                float v2 = 0.0f;
                #pragma unroll
                for (int w2 = 0; w2 < 8; ++w2) v2 += sRED[(w2 * 64 + ln) * 4 + r];
                const float ht = tanh_fast(v2);
                if (p < 4)
                    st_u32_coh((unsigned*)(out + (size_t)t * (BB * HH) + b * HH + j0 + p),
                               __float_as_uint(ht));
                sSM[tid] = ht;
            }
            __syncthreads();
            ((f32x4*)sRED)[w * 64 + lane] = acc1;
            __syncthreads();
            if (tid >= 256) {  // batches 16..31
                const int b = tid >> 4, p = tid & 15;
                const int bi = b & 15;
                const int ln = ((bi >> 2) << 4) | p, r = bi & 3;
                float v2 = 0.0f;
                #pragma unroll
                for (int w2 = 0; w2 < 8; ++w2) v2 += sRED[(w2 * 64 + ln) * 4 + r];
                const float ht = tanh_fast(v2);
                if (p < 4)
                    st_u32_coh((unsigned*)(out + (size_t)t * (BB * HH) + b * HH + j0 + p),
                               __float_as_uint(ht));
                sSM[tid] = ht;
            }
            __syncthreads();
            if (tid < 64) {
                const int b2 = tid >> 1, pp = (tid & 1) * 2;
                union { _Float16 h[2]; unsigned u; } pk;
                pk.h[0] = (_Float16)sSM[b2 * 16 + pp];
                pk.h[1] = (_Float16)sSM[b2 * 16 + pp + 1];
                st_u32_coh((unsigned*)(h16 + (size_t)b2 * HH + j0 + pp), pk.u);
            }
        }
        ++round;
        gbar4(bar, round);
    }

    // final c carry -> global (bypass; k_fin's dispatch boundary sees it)
    if (tid < 128)
        st_u32_coh((unsigned*)&cbuf[(size_t)(tid >> 2) * HH + j0 + (tid & 3)],
                   __float_as_uint(sCB[tid]));
}

// ---------------------------------------------------------------------------
// OLD PATH kernels (fallback for small workspaces) -- unchanged
// ---------------------------------------------------------------------------
__global__ __launch_bounds__(64) void k_step1(const float* __restrict__ hprev,
                                              const _Float16* __restrict__ Whh_h,
                                              const float* __restrict__ Whh_f,
                                              const _Float16* __restrict__ gx_t,
                                              const float* __restrict__ xt_f,
                                              const _Float16* __restrict__ Wih_h,
                                              const float* __restrict__ Wih_f,
                                              const float* __restrict__ bsum,
                                              float* __restrict__ cbuf,
                                              float* __restrict__ hy,
                                              int use_pre, int staged) {
    const int wave = blockIdx.x;
    const int lane = threadIdx.x;
    const int m0 = (wave >> 6) * 16;
    const int j0 = (wave & 63) * 16;
    const int lm = lane & 15, q8 = (lane >> 4) * 8;

    f32x4 acc[4];
    #pragma unroll
    for (int q = 0; q < 4; ++q) acc[q] = (f32x4)0.0f;

    const float* arow = hprev + (size_t)(m0 + lm) * HH;
    if (staged) {
        for (int k0 = 0; k0 < HH; k0 += 32) {
            f16x8 a = cvt8(arow + k0 + q8);
            #pragma unroll
            for (int q = 0; q < 4; ++q) {
                f16x8 b = *(const f16x8*)(Whh_h + (size_t)(q * HH + j0 + lm) * HH + k0 + q8);
                acc[q] = __builtin_amdgcn_mfma_f32_16x16x32_f16(a, b, acc[q], 0, 0, 0);
            }
        }
    } else {
        for (int k0 = 0; k0 < HH; k0 += 32) {
            f16x8 a = cvt8(arow + k0 + q8);
            #pragma unroll
            for (int q = 0; q < 4; ++q) {
                f16x8 b = cvt8(Whh_f + (size_t)(q * HH + j0 + lm) * HH + k0 + q8);
                acc[q] = __builtin_amdgcn_mfma_f32_16x16x32_f16(a, b, acc[q], 0, 0, 0);
            }
        }
    }
    if (!use_pre) {
        const float* xrow = xt_f + (size_t)(m0 + lm) * DD;
        if (staged) {
            for (int k0 = 0; k0 < DD; k0 += 32) {
                f16x8 a = cvt8(xrow + k0 + q8);
                #pragma unroll
                for (int q = 0; q < 4; ++q) {
                    f16x8 b = *(const f16x8*)(Wih_h + (size_t)(q * HH + j0 + lm) * DD + k0 + q8);
                    acc[q] = __builtin_amdgcn_mfma_f32_16x16x32_f16(a, b, acc[q], 0, 0, 0);
                }
            }
        } else {
            for (int k0 = 0; k0 < DD; k0 += 32) {
                f16x8 a = cvt8(xrow + k0 + q8);
                #pragma unroll
                for (int q = 0; q < 4; ++q) {
                    f16x8 b = cvt8(Wih_f + (size_t)(q * HH + j0 + lm) * DD + k0 + q8);
                    acc[q] = __builtin_amdgcn_mfma_f32_16x16x32_f16(a, b, acc[q], 0, 0, 0);
                }
            }
        }
    }
    const int rq = (lane >> 4) * 4;
    const int j = j0 + lm;
    const float bs_i = bsum[j], bs_f = bsum[HH + j], bs_g = bsum[2 * HH + j], bs_o = bsum[3 * HH + j];
    #pragma unroll
    for (int r = 0; r < 4; ++r) {
        const int b = m0 + rq + r;
        float gi = acc[0][r] + bs_i, gf = acc[1][r] + bs_f;
        float gg = acc[2][r] + bs_g, go = acc[3][r] + bs_o;
        if (use_pre) {
            const _Float16* g = gx_t + (size_t)b * (4 * HH);
            gi += (float)g[j];
            gf += (float)g[HH + j];
            gg += (float)g[2 * HH + j];
            go += (float)g[3 * HH + j];
        }
        const float cprev = cbuf[b * HH + j];
        const float cy = sigm(gf) * cprev + sigm(gi) * tanh_fast(gg);
        const float hv = sigm(go) * tanh_fast(cy);
        cbuf[b * HH + j] = cy;
        hy[b * HH + j] = hv;
    }
}

__global__ __launch_bounds__(64) void k_target(const float* __restrict__ hy,
                                               const _Float16* __restrict__ Win_h,
                                               const float* __restrict__ Win_f,
                                               float* __restrict__ target,
                                               int staged) {
    const int wave = blockIdx.x;
    const int lane = threadIdx.x;
    const int m0 = (wave >> 6) * 16;
    const int j0 = (wave & 63) * 16;
    const int lm = lane & 15, q8 = (lane >> 4) * 8;

    f32x4 acc = (f32x4)0.0f;
    const float* arow = hy + (size_t)(m0 + lm) * HH;
    if (staged) {
        for (int k0 = 0; k0 < HH; k0 += 32) {
            f16x8 a = cvt8(arow + k0 + q8);
            f16x8 b = *(const f16x8*)(Win_h + (size_t)(j0 + lm) * HH + k0 + q8);
            acc = __builtin_amdgcn_mfma_f32_16x16x32_f16(a, b, acc, 0, 0, 0);
        }
    } else {
        for (int k0 = 0; k0 < HH; k0 += 32) {
            f16x8 a = cvt8(arow + k0 + q8);
            f16x8 b = cvt8(Win_f + (size_t)(j0 + lm) * HH + k0 + q8);
            acc = __builtin_amdgcn_mfma_f32_16x16x32_f16(a, b, acc, 0, 0, 0);
        }
    }
    const int rq = (lane >> 4) * 4;
    const int j = j0 + lm;
    #pragma unroll
    for (int r = 0; r < 4; ++r)
        target[(m0 + rq + r) * HH + j] = acc[r];
}

__global__ __launch_bounds__(256) void k_scores(const _Float16* __restrict__ ctx_h,
                                                const float* __restrict__ ctx_f,
                                                const float* __restrict__ target,
                                                float* __restrict__ scores, int staged) {
    const int idx = (blockIdx.x * blockDim.x + threadIdx.x) >> 6;  // b*512+s
    const int lane = threadIdx.x & 63;
    const int b = idx >> 9;
    const int s = idx & 511;
    const float* trow = target + b * HH + lane * 16;
    float4 t0 = *(const float4*)(trow);
    float4 t1 = *(const float4*)(trow + 4);
    float4 t2 = *(const float4*)(trow + 8);
    float4 t3 = *(const float4*)(trow + 12);
    float sum = 0.0f;
    if (staged) {
        const _Float16* crow = ctx_h + ((size_t)s * BB + b) * HH + lane * 16;
        f16x8 c0 = *(const f16x8*)(crow);
        f16x8 c1 = *(const f16x8*)(crow + 8);
        sum += (float)c0[0] * t0.x + (float)c0[1] * t0.y + (float)c0[2] * t0.z + (float)c0[3] * t0.w;
        sum += (float)c0[4] * t1.x + (float)c0[5] * t1.y + (float)c0[6] * t1.z + (float)c0[7] * t1.w;
        sum += (float)c1[0] * t2.x + (float)c1[1] * t2.y + (float)c1[2] * t2.z + (float)c1[3] * t2.w;
        sum += (float)c1[4] * t3.x + (float)c1[5] * t3.y + (float)c1[6] * t3.z + (float)c1[7] * t3.w;
    } else {
        const float* crow = ctx_f + ((size_t)s * BB + b) * HH + lane * 16;
        float4 c0 = *(const float4*)(crow);
        float4 c1 = *(const float4*)(crow + 4);
        float4 c2 = *(const float4*)(crow + 8);
        float4 c3 = *(const float4*)(crow + 12);
        sum += c0.x * t0.x + c0.y * t0.y + c0.z * t0.z + c0.w * t0.w;
        sum += c1.x * t1.x + c1.y * t1.y + c1.z * t1.z + c1.w * t1.w;
        sum += c2.x * t2.x + c2.y * t2.y + c2.z * t2.z + c2.w * t2.w;
        sum += c3.x * t3.x + c3.y * t3.y + c3.z * t3.z + c3.w * t3.w;
    }
    #pragma unroll
    for (int off = 32; off > 0; off >>= 1) sum += __shfl_down(sum, off, 64);
    if (lane == 0) scores[b * SS + s] = sum;
}

__global__ __launch_bounds__(256) void k_attn(const _Float16* __restrict__ ctx_h,
                                              const float* __restrict__ ctx_f,
                                              const float* __restrict__ scores,
                                              float* __restrict__ wc, int staged) {
    __shared__ float sm[SS];
    __shared__ float red[256];
    const int b = blockIdx.x >> 1;
    const int hc = blockIdx.x & 1;
    const int t = threadIdx.x;

    const float v0 = scores[b * SS + t];
    const float v1 = scores[b * SS + 256 + t];
    red[t] = fmaxf(v0, v1);
    __syncthreads();
    for (int o = 128; o > 0; o >>= 1) {
        if (t < o) red[t] = fmaxf(red[t], red[t + o]);
        __syncthreads();
    }
    const float mx = red[0];
    __syncthreads();
    const float e0 = __expf(v0 - mx);
    const float e1 = __expf(v1 - mx);
    sm[t] = e0;
    sm[t + 256] = e1;
    red[t] = e0 + e1;
    __syncthreads();
    for (int o = 128; o > 0; o >>= 1) {
        if (t < o) red[t] += red[t + o];
        __syncthreads();
    }
    const float inv = 1.0f / red[0];

    const int h = hc * 512 + t * 2;
    float a0 = 0.0f, a1 = 0.0f;
    if (staged) {
        const _Float16* cbase = ctx_h + (size_t)b * HH + h;
        #pragma unroll 8
        for (int s = 0; s < SS; ++s) {
            const float a = sm[s];
            const f16x2 u = *(const f16x2*)(cbase + (size_t)s * (BB * HH));
            a0 += a * (float)u[0];
            a1 += a * (float)u[1];
        }
    } else {
        const float* cbase = ctx_f + (size_t)b * HH + h;
        #pragma unroll 8
        for (int s = 0; s < SS; ++s) {
            const float a = sm[s];
            const float2 u = *(const float2*)(cbase + (size_t)s * (BB * HH));
            a0 += a * u.x;
            a1 += a * u.y;
        }
    }
    wc[b * HH + h] = a0 * inv;
    wc[b * HH + h + 1] = a1 * inv;
}

__global__ __launch_bounds__(64) void k_out(const float* __restrict__ wc,
                                            const float* __restrict__ hy,
                                            const _Float16* __restrict__ Wout_h,
                                            const float* __restrict__ Wout_f,
                                            float* __restrict__ out_t,
                                            int staged) {
    const int wave = blockIdx.x;
    const int lane = threadIdx.x;
    const int m0 = (wave >> 6) * 16;
    const int j0 = (wave & 63) * 16;
    const int lm = lane & 15, q8 = (lane >> 4) * 8;

    f32x4 acc = (f32x4)0.0f;
    const float* arow1 = wc + (size_t)(m0 + lm) * HH;
    const float* arow2 = hy + (size_t)(m0 + lm) * HH;
    if (staged) {
        const _Float16* brow = Wout_h + (size_t)(j0 + lm) * (2 * HH);
        for (int k0 = 0; k0 < HH; k0 += 32) {
            f16x8 a = cvt8(arow1 + k0 + q8);
            f16x8 b = *(const f16x8*)(brow + k0 + q8);
            acc = __builtin_amdgcn_mfma_f32_16x16x32_f16(a, b, acc, 0, 0, 0);
        }
        for (int k0 = 0; k0 < HH; k0 += 32) {
            f16x8 a = cvt8(arow2 + k0 + q8);
            f16x8 b = *(const f16x8*)(brow + HH + k0 + q8);
            acc = __builtin_amdgcn_mfma_f32_16x16x32_f16(a, b, acc, 0, 0, 0);
        }
    } else {
        const float* brow = Wout_f + (size_t)(j0 + lm) * (2 * HH);
        for (int k0 = 0; k0 < HH; k0 += 32) {
            f16x8 a = cvt8(arow1 + k0 + q8);
            f16x8 b = cvt8(brow + k0 + q8);
            acc = __builtin_amdgcn_mfma_f32_16x16x32_f16(a, b, acc, 0, 0, 0);
        }
        for (int k0 = 0; k0 < HH; k0 += 32) {
            f16x8 a = cvt8(arow2 + k0 + q8);
            f16x8 b = cvt8(brow + HH + k0 + q8);
            acc = __builtin_amdgcn_mfma_f32_16x16x32_f16(a, b, acc, 0, 0, 0);
        }
    }
    const int rq = (lane >> 4) * 4;
    const int j = j0 + lm;
    #pragma unroll
    for (int r = 0; r < 4; ++r)
        out_t[(m0 + rq + r) * HH + j] = tanh_fast(acc[r]);
}

// ---------------------------------------------------------------------------
// new-path workspace layout
// ---------------------------------------------------------------------------
static constexpr size_t NW_CBUF   = 0;          // 131072
static constexpr size_t NW_SCORES = 131072;     //  65536
static constexpr size_t NW_HY16   = 196608;     //  65536
static constexpr size_t NW_H16    = 262144;     //  65536
static constexpr size_t NW_WC16   = 327680;     //  65536
static constexpr size_t NW_BSUM   = 393216;     //  16384
static constexpr size_t NW_BAR    = 409600;     //   4096
static constexpr size_t NW_WINT   = 413696;     // 2097152
static constexpr size_t NW_X16    = 2510848;    // 33554432
static constexpr size_t NW_CTXH   = 36065280;   // 33554432
static constexpr size_t NW_CTXW   = 69619712;   // 33554432
static constexpr size_t NW_TOTAL  = 103174144;

extern "C" void kernel_launch(void* const* d_in, const int* in_sizes, int n_in,
                              void* d_out, int out_size, void* d_ws, size_t ws_size,
                              hipStream_t stream) {
    const float* x    = (const float*)d_in[0];
    const float* h0   = (const float*)d_in[1];
    const float* c0   = (const float*)d_in[2];
    const float* ctx  = (const float*)d_in[3];
    const float* Wih  = (const float*)d_in[4];
    const float* bih  = (const float*)d_in[5];
    const float* Whh  = (const float*)d_in[6];
    const float* bhh  = (const float*)d_in[7];
    const float* Win  = (const float*)d_in[8];
    const float* Wout = (const float*)d_in[9];
    float* out = (float*)d_out;
    char* ws = (char*)d_ws;

    if (ws_size >= NW_TOTAL) {
        // ---------------- persistent-kernel path ----------------
        float* cbuf       = (float*)(ws + NW_CBUF);
        float* scores     = (float*)(ws + NW_SCORES);
        _Float16* hy16    = (_Float16*)(ws + NW_HY16);
        _Float16* h16     = (_Float16*)(ws + NW_H16);
        _Float16* wc16    = (_Float16*)(ws + NW_WC16);
        float* bsum       = (float*)(ws + NW_BSUM);
        unsigned* bar     = (unsigned*)(ws + NW_BAR);
        _Float16* WinT    = (_Float16*)(ws + NW_WINT);
        _Float16* x16     = (_Float16*)(ws + NW_X16);
        _Float16* ctx_h   = (_Float16*)(ws + NW_CTXH);
        _Float16* ctxW    = (_Float16*)(ws + NW_CTXW);

        k_bias<<<16, 256, 0, stream>>>(bih, bhh, bsum);
        k_zero<<<4, 256, 0, stream>>>(bar);
        k_cvt<<<2048, 256, 0, stream>>>(ctx, ctx_h, SS * BB * HH / 4);
        k_cvt<<<4096, 256, 0, stream>>>(x, x16, TT * BB * DD / 4);
        k_cvt<<<32, 256, 0, stream>>>(h0, h16, BB * HH / 4);
        k_trwin<<<1024, 256, 0, stream>>>(Win, WinT);
        k_ctxw<<<1024, 256, 0, stream>>>(ctx, WinT, ctxW);

        k_persist<<<256, 512, 0, stream>>>(x16, ctx_h, ctxW, Whh, Wih, Wout, bsum,
                                           c0, cbuf, h16, hy16, wc16, scores, out, bar);

        float* hT = out + (size_t)TT * BB * HH;
        float* cT = hT + BB * HH;
        k_fin<<<128, 256, 0, stream>>>(out + (size_t)(TT - 1) * BB * HH, cbuf, hT, cT);
        return;
    }

    // ---------------- old path (fallback, unchanged) ----------------
    float* cbuf   = (float*)(ws + 0);        // 131072
    float* hy     = (float*)(ws + 131072);   // 131072
    float* target = (float*)(ws + 262144);   // 131072
    float* scores = (float*)(ws + 393216);   //  65536
    float* wc     = (float*)(ws + 458752);   // 131072
    float* bsum   = (float*)(ws + 589824);   //  16384
    _Float16* Whh_h  = (_Float16*)(ws + 606208);    //  8388608
    _Float16* Win_h  = (_Float16*)(ws + 8994816);   //  2097152
    _Float16* Wout_h = (_Float16*)(ws + 11091968);  //  4194304
    _Float16* Wih_h  = (_Float16*)(ws + 15286272);  //  8388608
    _Float16* ctx_h  = (_Float16*)(ws + 23674880);  // 33554432
    _Float16* gx     = (_Float16*)(ws + 57229312);  // 134217728

    const int staged  = (ws_size >= (size_t)57229312) ? 1 : 0;
    const int use_pre = (ws_size >= (size_t)191447040) ? 1 : 0;

    k_bias<<<16, 256, 0, stream>>>(bih, bhh, bsum);
    k_init<<<128, 256, 0, stream>>>(c0, cbuf);
    if (staged) {
        k_cvt<<<1024, 256, 0, stream>>>(Whh, Whh_h, 4 * HH * HH / 4);
        k_cvt<<<1024, 256, 0, stream>>>(Win, Win_h, HH * HH / 4);
        k_cvt<<<1024, 256, 0, stream>>>(Wout, Wout_h, 2 * HH * HH / 4);
        k_cvt<<<2048, 256, 0, stream>>>(ctx, ctx_h, SS * BB * HH / 4);
        if (!use_pre) k_cvt<<<1024, 256, 0, stream>>>(Wih, Wih_h, 4 * HH * DD / 4);
    }
    if (use_pre) k_pre<<<4096, 256, 0, stream>>>(x, Wih, gx);

    for (int t = 0; t < TT; ++t) {
        const float* hprev = (t == 0) ? h0 : (out + (size_t)(t - 1) * BB * HH);
        const _Float16* gx_t = gx + (size_t)t * BB * 4 * HH;
        const float* xt = x + (size_t)t * BB * DD;
        float* out_t = out + (size_t)t * BB * HH;

        k_step1<<<128, 64, 0, stream>>>(hprev, Whh_h, Whh, gx_t, xt, Wih_h, Wih,
                                        bsum, cbuf, hy, use_pre, staged);
        k_target<<<128, 64, 0, stream>>>(hy, Win_h, Win, target, staged);
        k_scores<<<4096, 256, 0, stream>>>(ctx_h, ctx, target, scores, staged);
        k_attn<<<64, 256, 0, stream>>>(ctx_h, ctx, scores, wc, staged);
        k_out<<<128, 64, 0, stream>>>(wc, hy, Wout_h, Wout, out_t, staged);
    }

    float* hT = out + (size_t)TT * BB * HH;
    float* cT = hT + BB * HH;
    k_fin<<<128, 256, 0, stream>>>(out + (size_t)(TT - 1) * BB * HH, cbuf, hT, cT);
}

// Round 9
// 22061.772 us; speedup vs baseline: 1.8760x; 1.1278x over previous
//
#include <hip/hip_runtime.h>
#include <hip/hip_bf16.h>
#include <cstdint>
#include <cstddef>

// Problem constants
#define TT 512
#define BB 32
#define DD 1024
#define HH 1024
#define SS 512

typedef _Float16 f16x8 __attribute__((ext_vector_type(8)));
typedef _Float16 f16x4 __attribute__((ext_vector_type(4)));
typedef _Float16 f16x2 __attribute__((ext_vector_type(2)));
typedef float f32x4 __attribute__((ext_vector_type(4)));

__device__ __forceinline__ float sigm(float x) { return 1.0f / (1.0f + __expf(-x)); }
__device__ __forceinline__ float tanh_fast(float x) {
    return 1.0f - 2.0f / (__expf(2.0f * x) + 1.0f);  // saturates, no inf/inf
}
// load 8 contiguous fp32, round to fp16 MFMA fragment
__device__ __forceinline__ f16x8 cvt8(const float* __restrict__ p) {
    float4 u = *(const float4*)p;
    float4 v = *(const float4*)(p + 4);
    f16x8 r;
    r[0] = (_Float16)u.x; r[1] = (_Float16)u.y; r[2] = (_Float16)u.z; r[3] = (_Float16)u.w;
    r[4] = (_Float16)v.x; r[5] = (_Float16)v.y; r[6] = (_Float16)v.z; r[7] = (_Float16)v.w;
    return r;
}

// ---------------------------------------------------------------------------
// Cache-bypassing (coherent-point) helpers. Relaxed agent-scope atomic STORES
// bypass per-XCD L1/L2 and land at MALL (required: MALL fetch by readers must
// see the data). Bypass LOADS are HBM-served and slow (~800 GB/s cap measured
// R5/R8) — used only for tiny data (scores, flags) in the ring path.
// ---------------------------------------------------------------------------
__device__ __forceinline__ void st_u32_coh(unsigned* p, unsigned v) {
    __hip_atomic_store(p, v, __ATOMIC_RELAXED, __HIP_MEMORY_SCOPE_AGENT);
}
__device__ __forceinline__ unsigned ld_u32_coh(const unsigned* p) {
    return __hip_atomic_load(p, __ATOMIC_RELAXED, __HIP_MEMORY_SCOPE_AGENT);
}
__device__ __forceinline__ unsigned long long ld_u64_coh(const unsigned long long* p) {
    return __hip_atomic_load(p, __ATOMIC_RELAXED, __HIP_MEMORY_SCOPE_AGENT);
}
__device__ __forceinline__ f16x8 ld16_coh(const _Float16* p) {
    union { unsigned long long q[2]; f16x8 h; } u;
    u.q[0] = ld_u64_coh((const unsigned long long*)p);
    u.q[1] = ld_u64_coh((const unsigned long long*)p + 1);
    return u.h;
}
// mixed read: ring path uses normal cached loads (write-once addresses ->
// no stale-line hazard; L2-shared per XCD), non-ring path uses bypass.
__device__ __forceinline__ f16x8 ld16_mix(const _Float16* p, bool coh) {
    return coh ? ld16_coh(p) : *(const f16x8*)p;
}

// ---------------------------------------------------------------------------
// staging: fp32 -> fp16 copy (grid-stride, float4 -> f16x4)
// ---------------------------------------------------------------------------
__global__ __launch_bounds__(256) void k_cvt(const float* __restrict__ s,
                                             _Float16* __restrict__ d, int n4) {
    for (int i = blockIdx.x * blockDim.x + threadIdx.x; i < n4; i += gridDim.x * blockDim.x) {
        float4 v = ((const float4*)s)[i];
        f16x4 h;
        h[0] = (_Float16)v.x; h[1] = (_Float16)v.y;
        h[2] = (_Float16)v.z; h[3] = (_Float16)v.w;
        ((f16x4*)d)[i] = h;
    }
}

__global__ void k_bias(const float* __restrict__ bih, const float* __restrict__ bhh,
                       float* __restrict__ bsum) {
    const int i = blockIdx.x * blockDim.x + threadIdx.x;
    if (i < 4 * HH) bsum[i] = bih[i] + bhh[i];
}

__global__ void k_init(const float* __restrict__ c0, float* __restrict__ cbuf) {
    const int i = blockIdx.x * blockDim.x + threadIdx.x;
    if (i < BB * HH) cbuf[i] = c0[i];
}

// zero the WHOLE barrier region (stale values from a previous graph replay
// would make every barrier fall through).
__global__ void k_zero(unsigned* __restrict__ p) {
    const int i = blockIdx.x * blockDim.x + threadIdx.x;
    if (i < 1024) p[i] = 0u;
}

__global__ void k_fin(const float* __restrict__ lasth, const float* __restrict__ cbuf,
                      float* __restrict__ hT, float* __restrict__ cT) {
    const int i = blockIdx.x * blockDim.x + threadIdx.x;
    if (i < BB * HH) {
        hT[i] = lasth[i];
        cT[i] = cbuf[i];
    }
}

// ---------------------------------------------------------------------------
// K_pre (old path only)
// ---------------------------------------------------------------------------
__global__ __launch_bounds__(256) void k_pre(const float* __restrict__ x,
                                             const float* __restrict__ Wih,
                                             _Float16* __restrict__ gx) {
    const int wave = (blockIdx.x * blockDim.x + threadIdx.x) >> 6;
    const int lane = threadIdx.x & 63;
    const int m0 = (wave >> 6) * 64, n0 = (wave & 63) * 64;
    const int lm = lane & 15, q8 = (lane >> 4) * 8;

    f32x4 acc[4][4];
    #pragma unroll
    for (int i = 0; i < 4; ++i)
        #pragma unroll
        for (int j = 0; j < 4; ++j) acc[i][j] = (f32x4)0.0f;

    for (int k0 = 0; k0 < DD; k0 += 32) {
        f16x8 a[4], b[4];
        #pragma unroll
        for (int i = 0; i < 4; ++i)
            a[i] = cvt8(x + (size_t)(m0 + i * 16 + lm) * DD + k0 + q8);
        #pragma unroll
        for (int j = 0; j < 4; ++j)
            b[j] = cvt8(Wih + (size_t)(n0 + j * 16 + lm) * DD + k0 + q8);
        #pragma unroll
        for (int i = 0; i < 4; ++i)
            #pragma unroll
            for (int j = 0; j < 4; ++j)
                acc[i][j] = __builtin_amdgcn_mfma_f32_16x16x32_f16(a[i], b[j], acc[i][j], 0, 0, 0);
    }
    const int rq = (lane >> 4) * 4;
    #pragma unroll
    for (int i = 0; i < 4; ++i)
        #pragma unroll
        for (int j = 0; j < 4; ++j)
            #pragma unroll
            for (int r = 0; r < 4; ++r)
                gx[(size_t)(m0 + i * 16 + rq + r) * (4 * HH) + n0 + j * 16 + lm] =
                    (_Float16)acc[i][j][r];
}

// ---------------------------------------------------------------------------
// k_trwin: WinT[k][j] = Win[j][k] as fp16 (one-time, for ctxW GEMM)
// ---------------------------------------------------------------------------
__global__ __launch_bounds__(256) void k_trwin(const float* __restrict__ Win,
                                               _Float16* __restrict__ WinT) {
    __shared__ float tile[32][33];
    const int bx = blockIdx.x & 31, by = blockIdx.x >> 5;
    const int tx = threadIdx.x & 31, ty = threadIdx.x >> 5;
    #pragma unroll
    for (int r = 0; r < 4; ++r)
        tile[ty + r * 8][tx] = Win[(size_t)(by * 32 + ty + r * 8) * HH + bx * 32 + tx];
    __syncthreads();
    #pragma unroll
    for (int r = 0; r < 4; ++r)
        WinT[(size_t)(bx * 32 + ty + r * 8) * HH + by * 32 + tx] =
            (_Float16)tile[tx][ty + r * 8];
}

// ---------------------------------------------------------------------------
// k_ctxw: ctxW[(s,b),k] = sum_j ctx[(s,b),j] * WinT[k,j]  (= ctx @ Win)
// ---------------------------------------------------------------------------
__global__ __launch_bounds__(256) void k_ctxw(const float* __restrict__ ctxf,
                                              const _Float16* __restrict__ WinT,
                                              _Float16* __restrict__ ctxW) {
    const int wave = (blockIdx.x * blockDim.x + threadIdx.x) >> 6;  // 4096 waves
    const int lane = threadIdx.x & 63;
    const int m0 = (wave >> 4) * 64, n0 = (wave & 15) * 64;
    const int lm = lane & 15, q8 = (lane >> 4) * 8;

    f32x4 acc[4][4];
    #pragma unroll
    for (int i = 0; i < 4; ++i)
        #pragma unroll
        for (int j = 0; j < 4; ++j) acc[i][j] = (f32x4)0.0f;

    for (int k0 = 0; k0 < HH; k0 += 32) {
        f16x8 a[4], b[4];
        #pragma unroll
        for (int i = 0; i < 4; ++i)
            a[i] = cvt8(ctxf + (size_t)(m0 + i * 16 + lm) * HH + k0 + q8);
        #pragma unroll
        for (int j = 0; j < 4; ++j)
            b[j] = *(const f16x8*)(WinT + (size_t)(n0 + j * 16 + lm) * HH + k0 + q8);
        #pragma unroll
        for (int i = 0; i < 4; ++i)
            #pragma unroll
            for (int j = 0; j < 4; ++j)
                acc[i][j] = __builtin_amdgcn_mfma_f32_16x16x32_f16(a[i], b[j], acc[i][j], 0, 0, 0);
    }
    const int rq = (lane >> 4) * 4;
    #pragma unroll
    for (int i = 0; i < 4; ++i)
        #pragma unroll
        for (int j = 0; j < 4; ++j)
            #pragma unroll
            for (int r = 0; r < 4; ++r)
                ctxW[(size_t)(m0 + i * 16 + rq + r) * HH + n0 + j * 16 + lm] =
                    (_Float16)acc[i][j][r];
}

// ---------------------------------------------------------------------------
// Grid barrier v4 (R5-proven): store-flag + all-poll, no RMW, no fence.
// ---------------------------------------------------------------------------
__device__ __forceinline__ void gbar4(unsigned* __restrict__ flags, unsigned round) {
    __syncthreads();  // drains all waves' bypass stores (vmcnt 0)
    const int tid = threadIdx.x;
    if (tid == 0) {
        asm volatile("s_waitcnt vmcnt(0)" ::: "memory");
        st_u32_coh(&flags[blockIdx.x], round);
    }
    if (tid < 64) {
        int guard = 0;
        for (;;) {
            const unsigned a0 = ld_u32_coh(&flags[tid * 4 + 0]);
            const unsigned a1 = ld_u32_coh(&flags[tid * 4 + 1]);
            const unsigned a2 = ld_u32_coh(&flags[tid * 4 + 2]);
            const unsigned a3 = ld_u32_coh(&flags[tid * 4 + 3]);
            if (a0 >= round && a1 >= round && a2 >= round && a3 >= round) break;
            __builtin_amdgcn_s_sleep(1);
            if (++guard > (1 << 20)) break;  // bail-out: wrong answer, not hang
        }
    }
    __syncthreads();
}

// ---------------------------------------------------------------------------
// Persistent kernel: whole 512-step scan in one launch.
// 256 blocks x 512 threads, 1 block/CU. 4 flag barriers/step.
// RING PATH (use_ring=1): per-step tensors are ring-buffered over all 512
// steps (hyring[t], wcring[t]; h-carry source = out[t-1] fp32). Every
// communicated address is WRITE-ONCE per launch -> readers use NORMAL CACHED
// loads with no stale-line hazard: first reader per XCD fills L2 from MALL
// (writers' bypass stores landed there pre-barrier), 31 others hit L2.
// This removes the ~36 MB/step of HBM-latency bypass reads (R5-R8 floor).
// Non-ring path (smaller ws): R8 behavior (fixed buffers + bypass reads).
// ---------------------------------------------------------------------------
__global__ __launch_bounds__(512, 1) void k_persist(
    const _Float16* __restrict__ x16,    // [T*B, D]
    const _Float16* __restrict__ ctx_h,  // [S*B, H]
    const _Float16* __restrict__ ctxW,   // [S*B, H]
    const float* __restrict__ Whh,       // [4H, H] fp32
    const float* __restrict__ Wih,       // [4H, D] fp32
    const float* __restrict__ Wout,      // [H, 2H] fp32
    const float* __restrict__ bsum,      // [4H]
    const float* __restrict__ h0f,       // [B, H] initial h (fp32)
    const float* __restrict__ c0i,       // [B, H] initial c
    float* __restrict__ cbuf,            // [B, H] fp32 final c out
    _Float16* __restrict__ h16,          // [B, H] h carry (non-ring)
    _Float16* __restrict__ hy16,         // [B, H] cell out (non-ring)
    _Float16* __restrict__ wc16,         // [B, H] weighted ctx (non-ring)
    _Float16* __restrict__ hyring,       // [T, B*H] (ring)
    _Float16* __restrict__ wcring,       // [T, B*H] (ring)
    float* __restrict__ scores,          // [B, S]
    float* __restrict__ out,             // [T, B, H] fp32 (also h-carry ring)
    unsigned* __restrict__ bar,
    int use_ring) {
    __shared__ __align__(16) _Float16 sWHH[16 * 1024];  // 32KB (P1 Whh slice)
    __shared__ __align__(16) _Float16 sWIH[16 * 1024];  // 32KB (P1 Wih slice)
    __shared__ __align__(16) _Float16 sWOUT[4 * 2048];  // 16KB (P4 Wout slice)
    __shared__ __align__(16) _Float16 sH[32 * 1024];    // 64KB gather tile
    __shared__ __align__(16) float sRED[2048];          // 8KB (two-stage reduces)
    __shared__ float sSM[512];                          // 2KB
    __shared__ float sCB[128];                          // c carry (32b x 4col)

    const int bid = blockIdx.x;
    const int tid = threadIdx.x;
    const int w = tid >> 6, lane = tid & 63;
    const int lm = lane & 15, q8 = (lane >> 4) * 8;
    const int j0 = bid * 4;  // P1/P4 column base (4 H-cols per block)
    const bool coh = !use_ring;

    // ---- one-time: stage weight slices fp32->fp16 into LDS (XOR-swizzled) ----
    for (int idx = tid; idx < 16 * 128; idx += 512) {
        const int p = idx >> 7, k8 = idx & 127;
        const int g = (p >> 2) * HH + j0 + (p & 3);  // gate (p>>2), col j0+(p&3)
        const int dst = (p * 2048 + k8 * 16) ^ ((p & 7) << 4);
        *(f16x8*)((char*)sWHH + dst) = cvt8(Whh + (size_t)g * HH + k8 * 8);
        *(f16x8*)((char*)sWIH + dst) = cvt8(Wih + (size_t)g * DD + k8 * 8);
    }
    for (int idx = tid; idx < 4 * 256; idx += 512) {
        const int p = idx >> 8, k8 = idx & 255;  // p = output col 0..3
        *(f16x8*)((char*)sWOUT + ((p * 4096 + k8 * 16) ^ (p << 4))) =
            cvt8(Wout + (size_t)(j0 + p) * (2 * HH) + k8 * 8);
    }
    if (tid < 128) sCB[tid] = c0i[(size_t)(tid >> 2) * HH + j0 + (tid & 3)];
    __syncthreads();

    unsigned round = 0;
    for (int t = 0; t < TT; ++t) {
        _Float16* hyb = use_ring ? (hyring + (size_t)t * (BB * HH)) : hy16;
        _Float16* wcb = use_ring ? (wcring + (size_t)t * (BB * HH)) : wc16;

        // ================= P1: gates + LSTM cell =================
        {
            // gather h-carry -> sH (swizzled rows)
            if (use_ring) {
                const float* hsrc = (t == 0) ? h0f : (out + (size_t)(t - 1) * (BB * HH));
                #pragma unroll
                for (int u = 0; u < 8; ++u) {
                    const int idx = u * 512 + tid;  // 0..4095
                    const int row = idx >> 7, c16 = idx & 127;
                    const f16x8 v = cvt8(hsrc + (size_t)row * HH + c16 * 8);
                    *(f16x8*)((char*)sH + ((row * 2048 + c16 * 16) ^ ((row & 7) << 4))) = v;
                }
            } else {
                #pragma unroll
                for (int u = 0; u < 8; ++u) {
                    const int idx = u * 512 + tid;
                    const int row = idx >> 7, c16 = idx & 127;
                    const f16x8 v = ld16_coh(h16 + (size_t)row * HH + c16 * 8);
                    *(f16x8*)((char*)sH + ((row * 2048 + c16 * 16) ^ ((row & 7) << 4))) = v;
                }
            }
            __syncthreads();
            const int kb = (w & 3) * 256;
            f32x4 acc0 = (f32x4)0.0f, acc1 = (f32x4)0.0f;
            if (w < 4) {
                #pragma unroll
                for (int kk = 0; kk < 256; kk += 32) {
                    const int k0 = kb + kk + q8;
                    f16x8 a0 = *(const f16x8*)((const char*)sH +
                                 ((lm * 2048 + k0 * 2) ^ ((lm & 7) << 4)));
                    f16x8 a1 = *(const f16x8*)((const char*)sH +
                                 (((16 + lm) * 2048 + k0 * 2) ^ ((lm & 7) << 4)));
                    f16x8 bb = *(const f16x8*)((const char*)sWHH +
                                 ((lm * 2048 + k0 * 2) ^ ((lm & 7) << 4)));
                    acc0 = __builtin_amdgcn_mfma_f32_16x16x32_f16(a0, bb, acc0, 0, 0, 0);
                    acc1 = __builtin_amdgcn_mfma_f32_16x16x32_f16(a1, bb, acc1, 0, 0, 0);
                }
            } else {
                const _Float16* Xb = x16 + (size_t)t * (BB * DD);
                #pragma unroll
                for (int kk = 0; kk < 256; kk += 32) {
                    const int k0 = kb + kk + q8;
                    f16x8 a0 = *(const f16x8*)(Xb + (size_t)lm * DD + k0);
                    f16x8 a1 = *(const f16x8*)(Xb + (size_t)(16 + lm) * DD + k0);
                    f16x8 bb = *(const f16x8*)((const char*)sWIH +
                                 ((lm * 2048 + k0 * 2) ^ ((lm & 7) << 4)));
                    acc0 = __builtin_amdgcn_mfma_f32_16x16x32_f16(a0, bb, acc0, 0, 0, 0);
                    acc1 = __builtin_amdgcn_mfma_f32_16x16x32_f16(a1, bb, acc1, 0, 0, 0);
                }
            }
            // two-stage reduce (fits 8KB sRED)
            ((f32x4*)sRED)[w * 64 + lane] = acc0;
            __syncthreads();
            if (tid < 256) {  // batches 0..15 (acc0)
                const int b = tid >> 4, p = tid & 15;
                const int bi = b & 15;
                const int ln = ((bi >> 2) << 4) | p, r = bi & 3;
                float gv = 0.0f;
                #pragma unroll
                for (int w2 = 0; w2 < 8; ++w2) gv += sRED[(w2 * 64 + ln) * 4 + r];
                sSM[tid] = gv;
            }
            __syncthreads();
            ((f32x4*)sRED)[w * 64 + lane] = acc1;
            __syncthreads();
            if (tid >= 256) {  // batches 16..31 (acc1)
                const int b = tid >> 4, p = tid & 15;
                const int bi = b & 15;
                const int ln = ((bi >> 2) << 4) | p, r = bi & 3;
                float gv = 0.0f;
                #pragma unroll
                for (int w2 = 0; w2 < 8; ++w2) gv += sRED[(w2 * 64 + ln) * 4 + r];
                sSM[tid] = gv;
            }
            __syncthreads();
            if (tid < 64) {
                const int b = tid >> 1, cp = (tid & 1) * 2;
                union { _Float16 h[2]; unsigned u; } pk;
                #pragma unroll
                for (int cc = 0; cc < 2; ++cc) {
                    const int c = cp + cc, j = j0 + c;
                    const float gi = sSM[b * 16 + 0 + c] + bsum[j];
                    const float gf = sSM[b * 16 + 4 + c] + bsum[HH + j];
                    const float gg = sSM[b * 16 + 8 + c] + bsum[2 * HH + j];
                    const float go = sSM[b * 16 + 12 + c] + bsum[3 * HH + j];
                    const float cprev = sCB[b * 4 + c];
                    const float cy = sigm(gf) * cprev + sigm(gi) * tanh_fast(gg);
                    const float hv = sigm(go) * tanh_fast(cy);
                    sCB[b * 4 + c] = cy;
                    pk.h[cc] = (_Float16)hv;
                }
                st_u32_coh((unsigned*)(hyb + (size_t)b * HH + j0 + cp), pk.u);
            }
        }
        ++round;
        gbar4(bar, round);

        // ================= P2: scores via cached ctxW stream =================
        {
            const int b = bid & 31, s0 = (bid >> 5) * 64;
            const _Float16* hrow = hyb + (size_t)b * HH + lane * 16;
            const f16x8 hv0 = ld16_mix(hrow, coh);
            const f16x8 hv1 = ld16_mix(hrow + 8, coh);
            float hf[16];
            #pragma unroll
            for (int i = 0; i < 8; ++i) { hf[i] = (float)hv0[i]; hf[8 + i] = (float)hv1[i]; }
            f16x8 cr0[8], cr1[8];
            #pragma unroll
            for (int i = 0; i < 8; ++i) {
                const _Float16* crow =
                    ctxW + ((size_t)(s0 + w * 8 + i) * BB + b) * HH + lane * 16;
                cr0[i] = *(const f16x8*)(crow);
                cr1[i] = *(const f16x8*)(crow + 8);
            }
            #pragma unroll
            for (int i = 0; i < 8; ++i) {
                float sum = 0.0f;
                #pragma unroll
                for (int jj = 0; jj < 8; ++jj)
                    sum += hf[jj] * (float)cr0[i][jj] + hf[8 + jj] * (float)cr1[i][jj];
                #pragma unroll
                for (int off = 32; off > 0; off >>= 1) sum += __shfl_down(sum, off, 64);
                if (lane == 0)
                    st_u32_coh((unsigned*)(scores + b * SS + s0 + w * 8 + i),
                               __float_as_uint(sum));
            }
        }
        ++round;
        gbar4(bar, round);

        // ========= P3: softmax + weighted context (cached ctx, 16B loads) =========
        {
            const int b = bid >> 3, h0 = (bid & 7) * 128;
            const float v =
                __uint_as_float(ld_u32_coh((const unsigned*)(scores + b * SS + tid)));
            float mx = v;
            #pragma unroll
            for (int off = 32; off > 0; off >>= 1) mx = fmaxf(mx, __shfl_xor(mx, off, 64));
            if (lane == 0) sRED[w] = mx;
            __syncthreads();
            mx = sRED[0];
            #pragma unroll
            for (int w2 = 1; w2 < 8; ++w2) mx = fmaxf(mx, sRED[w2]);
            const float e = __expf(v - mx);
            sSM[tid] = e;
            float ssum = e;
            #pragma unroll
            for (int off = 32; off > 0; off >>= 1) ssum += __shfl_xor(ssum, off, 64);
            if (lane == 0) sRED[8 + w] = ssum;
            __syncthreads();
            float tot = 0.0f;
            #pragma unroll
            for (int w2 = 0; w2 < 8; ++w2) tot += sRED[8 + w2];
            const float inv = 1.0f / tot;
            // wave w covers s in [w*64, w*64+64); lane = (g = s-subgroup, c = 8-col grp)
            const int g = lane >> 4, c = lane & 15;
            float acc[8];
            #pragma unroll
            for (int jj = 0; jj < 8; ++jj) acc[jj] = 0.0f;
            const _Float16* cb =
                ctx_h + ((size_t)(w * 64 + g) * BB + b) * HH + h0 + c * 8;
            #pragma unroll
            for (int i = 0; i < 16; ++i) {
                const float aw = sSM[w * 64 + g + i * 4];
                const f16x8 u = *(const f16x8*)(cb + (size_t)(i * 4) * (BB * HH));
                #pragma unroll
                for (int jj = 0; jj < 8; ++jj) acc[jj] += aw * (float)u[jj];
            }
            #pragma unroll
            for (int jj = 0; jj < 8; ++jj) {
                acc[jj] += __shfl_xor(acc[jj], 16, 64);
                acc[jj] += __shfl_xor(acc[jj], 32, 64);
            }
            __syncthreads();
            if (g == 0) {
                #pragma unroll
                for (int jj = 0; jj < 8; ++jj) sRED[w * 128 + c * 8 + jj] = acc[jj];
            }
            __syncthreads();
            if (tid < 64) {
                const int ccol = tid * 2;
                float sv0 = 0.0f, sv1 = 0.0f;
                #pragma unroll
                for (int w2 = 0; w2 < 8; ++w2) {
                    sv0 += sRED[w2 * 128 + ccol];
                    sv1 += sRED[w2 * 128 + ccol + 1];
                }
                union { _Float16 h[2]; unsigned u; } pk;
                pk.h[0] = (_Float16)(sv0 * inv);
                pk.h[1] = (_Float16)(sv1 * inv);
                st_u32_coh((unsigned*)(wcb + (size_t)b * HH + h0 + ccol), pk.u);
            }
        }
        ++round;
        gbar4(bar, round);

        // ===== P4: h_tilde = tanh([wc,hy]@Wout^T), gather sub-phases =====
        {
            const int pc = lm & 3;  // replicated output col 0..3
            const int kb = w * 128;
            f32x4 acc0 = (f32x4)0.0f, acc1 = (f32x4)0.0f;
            // sub-phase A: wc
            #pragma unroll
            for (int u = 0; u < 8; ++u) {
                const int idx = u * 512 + tid;
                const int row = idx >> 7, c16 = idx & 127;
                const f16x8 v = ld16_mix(wcb + (size_t)row * HH + c16 * 8, coh);
                *(f16x8*)((char*)sH + ((row * 2048 + c16 * 16) ^ ((row & 7) << 4))) = v;
            }
            __syncthreads();
            #pragma unroll
            for (int kk = 0; kk < 128; kk += 32) {
                const int k0 = kb + kk + q8;
                f16x8 a0 = *(const f16x8*)((const char*)sH +
                             ((lm * 2048 + k0 * 2) ^ ((lm & 7) << 4)));
                f16x8 a1 = *(const f16x8*)((const char*)sH +
                             (((16 + lm) * 2048 + k0 * 2) ^ ((lm & 7) << 4)));
                f16x8 bb = *(const f16x8*)((const char*)sWOUT +
                             ((pc * 4096 + k0 * 2) ^ (pc << 4)));
                acc0 = __builtin_amdgcn_mfma_f32_16x16x32_f16(a0, bb, acc0, 0, 0, 0);
                acc1 = __builtin_amdgcn_mfma_f32_16x16x32_f16(a1, bb, acc1, 0, 0, 0);
            }
            __syncthreads();  // all waves done reading sH before overwrite
            // sub-phase B: hy
            #pragma unroll
            for (int u = 0; u < 8; ++u) {
                const int idx = u * 512 + tid;
                const int row = idx >> 7, c16 = idx & 127;
                const f16x8 v = ld16_mix(hyb + (size_t)row * HH + c16 * 8, coh);
                *(f16x8*)((char*)sH + ((row * 2048 + c16 * 16) ^ ((row & 7) << 4))) = v;
            }
            __syncthreads();
            #pragma unroll
            for (int kk = 0; kk < 128; kk += 32) {
                const int k0 = kb + kk + q8;
                f16x8 a0 = *(const f16x8*)((const char*)sH +
                             ((lm * 2048 + k0 * 2) ^ ((lm & 7) << 4)));
                f16x8 a1 = *(const f16x8*)((const char*)sH +
                             (((16 + lm) * 2048 + k0 * 2) ^ ((lm & 7) << 4)));
                f16x8 bb = *(const f16x8*)((const char*)sWOUT +
                             ((pc * 4096 + (HH + k0) * 2) ^ (pc << 4)));
                acc0 = __builtin_amdgcn_mfma_f32_16x16x32_f16(a0, bb, acc0, 0, 0, 0);
                acc1 = __builtin_amdgcn_mfma_f32_16x16x32_f16(a1, bb, acc1, 0, 0, 0);
            }
            // two-stage reduce + epilogue
            ((f32x4*)sRED)[w * 64 + lane] = acc0;
            __syncthreads();
            if (tid < 256) {  // batches 0..15
                const int b = tid >> 4, p = tid & 15;
                const int bi = b & 15;
                const int ln = ((bi >> 2) << 4) | p, r = bi & 3;
                float v2 = 0.0f;
                #pragma unroll
                for (int w2 = 0; w2 < 8; ++w2) v2 += sRED[(w2 * 64 + ln) * 4 + r];
                const float ht = tanh_fast(v2);
                if (p < 4)
                    st_u32_coh((unsigned*)(out + (size_t)t * (BB * HH) + b * HH + j0 + p),
                               __float_as_uint(ht));
                sSM[tid] = ht;
            }
            __syncthreads();
            ((f32x4*)sRED)[w * 64 + lane] = acc1;
            __syncthreads();
            if (tid >= 256) {  // batches 16..31
                const int b = tid >> 4, p = tid & 15;
                const int bi = b & 15;
                const int ln = ((bi >> 2) << 4) | p, r = bi & 3;
                float v2 = 0.0f;
                #pragma unroll
                for (int w2 = 0; w2 < 8; ++w2) v2 += sRED[(w2 * 64 + ln) * 4 + r];
                const float ht = tanh_fast(v2);
                if (p < 4)
                    st_u32_coh((unsigned*)(out + (size_t)t * (BB * HH) + b * HH + j0 + p),
                               __float_as_uint(ht));
                sSM[tid] = ht;
            }
            __syncthreads();
            if (!use_ring && tid < 64) {
                const int b2 = tid >> 1, pp = (tid & 1) * 2;
                union { _Float16 h[2]; unsigned u; } pk;
                pk.h[0] = (_Float16)sSM[b2 * 16 + pp];
                pk.h[1] = (_Float16)sSM[b2 * 16 + pp + 1];
                st_u32_coh((unsigned*)(h16 + (size_t)b2 * HH + j0 + pp), pk.u);
            }
        }
        ++round;
        gbar4(bar, round);
    }

    // final c carry -> global (bypass; k_fin's dispatch boundary sees it)
    if (tid < 128)
        st_u32_coh((unsigned*)&cbuf[(size_t)(tid >> 2) * HH + j0 + (tid & 3)],
                   __float_as_uint(sCB[tid]));
}

// ---------------------------------------------------------------------------
// OLD PATH kernels (fallback for small workspaces) -- unchanged
// ---------------------------------------------------------------------------
__global__ __launch_bounds__(64) void k_step1(const float* __restrict__ hprev,
                                              const _Float16* __restrict__ Whh_h,
                                              const float* __restrict__ Whh_f,
                                              const _Float16* __restrict__ gx_t,
                                              const float* __restrict__ xt_f,
                                              const _Float16* __restrict__ Wih_h,
                                              const float* __restrict__ Wih_f,
                                              const float* __restrict__ bsum,
                                              float* __restrict__ cbuf,
                                              float* __restrict__ hy,
                                              int use_pre, int staged) {
    const int wave = blockIdx.x;
    const int lane = threadIdx.x;
    const int m0 = (wave >> 6) * 16;
    const int j0 = (wave & 63) * 16;
    const int lm = lane & 15, q8 = (lane >> 4) * 8;

    f32x4 acc[4];
    #pragma unroll
    for (int q = 0; q < 4; ++q) acc[q] = (f32x4)0.0f;

    const float* arow = hprev + (size_t)(m0 + lm) * HH;
    if (staged) {
        for (int k0 = 0; k0 < HH; k0 += 32) {
            f16x8 a = cvt8(arow + k0 + q8);
            #pragma unroll
            for (int q = 0; q < 4; ++q) {
                f16x8 b = *(const f16x8*)(Whh_h + (size_t)(q * HH + j0 + lm) * HH + k0 + q8);
                acc[q] = __builtin_amdgcn_mfma_f32_16x16x32_f16(a, b, acc[q], 0, 0, 0);
            }
        }
    } else {
        for (int k0 = 0; k0 < HH; k0 += 32) {
            f16x8 a = cvt8(arow + k0 + q8);
            #pragma unroll
            for (int q = 0; q < 4; ++q) {
                f16x8 b = cvt8(Whh_f + (size_t)(q * HH + j0 + lm) * HH + k0 + q8);
                acc[q] = __builtin_amdgcn_mfma_f32_16x16x32_f16(a, b, acc[q], 0, 0, 0);
            }
        }
    }
    if (!use_pre) {
        const float* xrow = xt_f + (size_t)(m0 + lm) * DD;
        if (staged) {
            for (int k0 = 0; k0 < DD; k0 += 32) {
                f16x8 a = cvt8(xrow + k0 + q8);
                #pragma unroll
                for (int q = 0; q < 4; ++q) {
                    f16x8 b = *(const f16x8*)(Wih_h + (size_t)(q * HH + j0 + lm) * DD + k0 + q8);
                    acc[q] = __builtin_amdgcn_mfma_f32_16x16x32_f16(a, b, acc[q], 0, 0, 0);
                }
            }
        } else {
            for (int k0 = 0; k0 < DD; k0 += 32) {
                f16x8 a = cvt8(xrow + k0 + q8);
                #pragma unroll
                for (int q = 0; q < 4; ++q) {
                    f16x8 b = cvt8(Wih_f + (size_t)(q * HH + j0 + lm) * DD + k0 + q8);
                    acc[q] = __builtin_amdgcn_mfma_f32_16x16x32_f16(a, b, acc[q], 0, 0, 0);
                }
            }
        }
    }
    const int rq = (lane >> 4) * 4;
    const int j = j0 + lm;
    const float bs_i = bsum[j], bs_f = bsum[HH + j], bs_g = bsum[2 * HH + j], bs_o = bsum[3 * HH + j];
    #pragma unroll
    for (int r = 0; r < 4; ++r) {
        const int b = m0 + rq + r;
        float gi = acc[0][r] + bs_i, gf = acc[1][r] + bs_f;
        float gg = acc[2][r] + bs_g, go = acc[3][r] + bs_o;
        if (use_pre) {
            const _Float16* g = gx_t + (size_t)b * (4 * HH);
            gi += (float)g[j];
            gf += (float)g[HH + j];
            gg += (float)g[2 * HH + j];
            go += (float)g[3 * HH + j];
        }
        const float cprev = cbuf[b * HH + j];
        const float cy = sigm(gf) * cprev + sigm(gi) * tanh_fast(gg);
        const float hv = sigm(go) * tanh_fast(cy);
        cbuf[b * HH + j] = cy;
        hy[b * HH + j] = hv;
    }
}

__global__ __launch_bounds__(64) void k_target(const float* __restrict__ hy,
                                               const _Float16* __restrict__ Win_h,
                                               const float* __restrict__ Win_f,
                                               float* __restrict__ target,
                                               int staged) {
    const int wave = blockIdx.x;
    const int lane = threadIdx.x;
    const int m0 = (wave >> 6) * 16;
    const int j0 = (wave & 63) * 16;
    const int lm = lane & 15, q8 = (lane >> 4) * 8;

    f32x4 acc = (f32x4)0.0f;
    const float* arow = hy + (size_t)(m0 + lm) * HH;
    if (staged) {
        for (int k0 = 0; k0 < HH; k0 += 32) {
            f16x8 a = cvt8(arow + k0 + q8);
            f16x8 b = *(const f16x8*)(Win_h + (size_t)(j0 + lm) * HH + k0 + q8);
            acc = __builtin_amdgcn_mfma_f32_16x16x32_f16(a, b, acc, 0, 0, 0);
        }
    } else {
        for (int k0 = 0; k0 < HH; k0 += 32) {
            f16x8 a = cvt8(arow + k0 + q8);
            f16x8 b = cvt8(Win_f + (size_t)(j0 + lm) * HH + k0 + q8);
            acc = __builtin_amdgcn_mfma_f32_16x16x32_f16(a, b, acc, 0, 0, 0);
        }
    }
    const int rq = (lane >> 4) * 4;
    const int j = j0 + lm;
    #pragma unroll
    for (int r = 0; r < 4; ++r)
        target[(m0 + rq + r) * HH + j] = acc[r];
}

__global__ __launch_bounds__(256) void k_scores(const _Float16* __restrict__ ctx_h,
                                                const float* __restrict__ ctx_f,
                                                const float* __restrict__ target,
                                                float* __restrict__ scores, int staged) {
    const int idx = (blockIdx.x * blockDim.x + threadIdx.x) >> 6;  // b*512+s
    const int lane = threadIdx.x & 63;
    const int b = idx >> 9;
    const int s = idx & 511;
    const float* trow = target + b * HH + lane * 16;
    float4 t0 = *(const float4*)(trow);
    float4 t1 = *(const float4*)(trow + 4);
    float4 t2 = *(const float4*)(trow + 8);
    float4 t3 = *(const float4*)(trow + 12);
    float sum = 0.0f;
    if (staged) {
        const _Float16* crow = ctx_h + ((size_t)s * BB + b) * HH + lane * 16;
        f16x8 c0 = *(const f16x8*)(crow);
        f16x8 c1 = *(const f16x8*)(crow + 8);
        sum += (float)c0[0] * t0.x + (float)c0[1] * t0.y + (float)c0[2] * t0.z + (float)c0[3] * t0.w;
        sum += (float)c0[4] * t1.x + (float)c0[5] * t1.y + (float)c0[6] * t1.z + (float)c0[7] * t1.w;
        sum += (float)c1[0] * t2.x + (float)c1[1] * t2.y + (float)c1[2] * t2.z + (float)c1[3] * t2.w;
        sum += (float)c1[4] * t3.x + (float)c1[5] * t3.y + (float)c1[6] * t3.z + (float)c1[7] * t3.w;
    } else {
        const float* crow = ctx_f + ((size_t)s * BB + b) * HH + lane * 16;
        float4 c0 = *(const float4*)(crow);
        float4 c1 = *(const float4*)(crow + 4);
        float4 c2 = *(const float4*)(crow + 8);
        float4 c3 = *(const float4*)(crow + 12);
        sum += c0.x * t0.x + c0.y * t0.y + c0.z * t0.z + c0.w * t0.w;
        sum += c1.x * t1.x + c1.y * t1.y + c1.z * t1.z + c1.w * t1.w;
        sum += c2.x * t2.x + c2.y * t2.y + c2.z * t2.z + c2.w * t2.w;
        sum += c3.x * t3.x + c3.y * t3.y + c3.z * t3.z + c3.w * t3.w;
    }
    #pragma unroll
    for (int off = 32; off > 0; off >>= 1) sum += __shfl_down(sum, off, 64);
    if (lane == 0) scores[b * SS + s] = sum;
}

__global__ __launch_bounds__(256) void k_attn(const _Float16* __restrict__ ctx_h,
                                              const float* __restrict__ ctx_f,
                                              const float* __restrict__ scores,
                                              float* __restrict__ wc, int staged) {
    __shared__ float sm[SS];
    __shared__ float red[256];
    const int b = blockIdx.x >> 1;
    const int hc = blockIdx.x & 1;
    const int t = threadIdx.x;

    const float v0 = scores[b * SS + t];
    const float v1 = scores[b * SS + 256 + t];
    red[t] = fmaxf(v0, v1);
    __syncthreads();
    for (int o = 128; o > 0; o >>= 1) {
        if (t < o) red[t] = fmaxf(red[t], red[t + o]);
        __syncthreads();
    }
    const float mx = red[0];
    __syncthreads();
    const float e0 = __expf(v0 - mx);
    const float e1 = __expf(v1 - mx);
    sm[t] = e0;
    sm[t + 256] = e1;
    red[t] = e0 + e1;
    __syncthreads();
    for (int o = 128; o > 0; o >>= 1) {
        if (t < o) red[t] += red[t + o];
        __syncthreads();
    }
    const float inv = 1.0f / red[0];

    const int h = hc * 512 + t * 2;
    float a0 = 0.0f, a1 = 0.0f;
    if (staged) {
        const _Float16* cbase = ctx_h + (size_t)b * HH + h;
        #pragma unroll 8
        for (int s = 0; s < SS; ++s) {
            const float a = sm[s];
            const f16x2 u = *(const f16x2*)(cbase + (size_t)s * (BB * HH));
            a0 += a * (float)u[0];
            a1 += a * (float)u[1];
        }
    } else {
        const float* cbase = ctx_f + (size_t)b * HH + h;
        #pragma unroll 8
        for (int s = 0; s < SS; ++s) {
            const float a = sm[s];
            const float2 u = *(const float2*)(cbase + (size_t)s * (BB * HH));
            a0 += a * u.x;
            a1 += a * u.y;
        }
    }
    wc[b * HH + h] = a0 * inv;
    wc[b * HH + h + 1] = a1 * inv;
}

__global__ __launch_bounds__(64) void k_out(const float* __restrict__ wc,
                                            const float* __restrict__ hy,
                                            const _Float16* __restrict__ Wout_h,
                                            const float* __restrict__ Wout_f,
                                            float* __restrict__ out_t,
                                            int staged) {
    const int wave = blockIdx.x;
    const int lane = threadIdx.x;
    const int m0 = (wave >> 6) * 16;
    const int j0 = (wave & 63) * 16;
    const int lm = lane & 15, q8 = (lane >> 4) * 8;

    f32x4 acc = (f32x4)0.0f;
    const float* arow1 = wc + (size_t)(m0 + lm) * HH;
    const float* arow2 = hy + (size_t)(m0 + lm) * HH;
    if (staged) {
        const _Float16* brow = Wout_h + (size_t)(j0 + lm) * (2 * HH);
        for (int k0 = 0; k0 < HH; k0 += 32) {
            f16x8 a = cvt8(arow1 + k0 + q8);
            f16x8 b = *(const f16x8*)(brow + k0 + q8);
            acc = __builtin_amdgcn_mfma_f32_16x16x32_f16(a, b, acc, 0, 0, 0);
        }
        for (int k0 = 0; k0 < HH; k0 += 32) {
            f16x8 a = cvt8(arow2 + k0 + q8);
            f16x8 b = *(const f16x8*)(brow + HH + k0 + q8);
            acc = __builtin_amdgcn_mfma_f32_16x16x32_f16(a, b, acc, 0, 0, 0);
        }
    } else {
        const float* brow = Wout_f + (size_t)(j0 + lm) * (2 * HH);
        for (int k0 = 0; k0 < HH; k0 += 32) {
            f16x8 a = cvt8(arow1 + k0 + q8);
            f16x8 b = cvt8(brow + k0 + q8);
            acc = __builtin_amdgcn_mfma_f32_16x16x32_f16(a, b, acc, 0, 0, 0);
        }
        for (int k0 = 0; k0 < HH; k0 += 32) {
            f16x8 a = cvt8(arow2 + k0 + q8);
            f16x8 b = cvt8(brow + HH + k0 + q8);
            acc = __builtin_amdgcn_mfma_f32_16x16x32_f16(a, b, acc, 0, 0, 0);
        }
    }
    const int rq = (lane >> 4) * 4;
    const int j = j0 + lm;
    #pragma unroll
    for (int r = 0; r < 4; ++r)
        out_t[(m0 + rq + r) * HH + j] = tanh_fast(acc[r]);
}

// ---------------------------------------------------------------------------
// new-path workspace layout (R8 base + rings appended)
// ---------------------------------------------------------------------------
static constexpr size_t NW_CBUF   = 0;          // 131072
static constexpr size_t NW_SCORES = 131072;     //  65536
static constexpr size_t NW_HY16   = 196608;     //  65536
static constexpr size_t NW_H16    = 262144;     //  65536
static constexpr size_t NW_WC16   = 327680;     //  65536
static constexpr size_t NW_BSUM   = 393216;     //  16384
static constexpr size_t NW_BAR    = 409600;     //   4096
static constexpr size_t NW_WINT   = 413696;     // 2097152
static constexpr size_t NW_X16    = 2510848;    // 33554432
static constexpr size_t NW_CTXH   = 36065280;   // 33554432
static constexpr size_t NW_CTXW   = 69619712;   // 33554432
static constexpr size_t NW_TOTAL  = 103174144;
static constexpr size_t NW_HYRING = 103174144;  // 33554432
static constexpr size_t NW_WCRING = 136728576;  // 33554432
static constexpr size_t NW_RING_TOTAL = 170283008;

extern "C" void kernel_launch(void* const* d_in, const int* in_sizes, int n_in,
                              void* d_out, int out_size, void* d_ws, size_t ws_size,
                              hipStream_t stream) {
    const float* x    = (const float*)d_in[0];
    const float* h0   = (const float*)d_in[1];
    const float* c0   = (const float*)d_in[2];
    const float* ctx  = (const float*)d_in[3];
    const float* Wih  = (const float*)d_in[4];
    const float* bih  = (const float*)d_in[5];
    const float* Whh  = (const float*)d_in[6];
    const float* bhh  = (const float*)d_in[7];
    const float* Win  = (const float*)d_in[8];
    const float* Wout = (const float*)d_in[9];
    float* out = (float*)d_out;
    char* ws = (char*)d_ws;

    if (ws_size >= NW_TOTAL) {
        // ---------------- persistent-kernel path ----------------
        float* cbuf       = (float*)(ws + NW_CBUF);
        float* scores     = (float*)(ws + NW_SCORES);
        _Float16* hy16    = (_Float16*)(ws + NW_HY16);
        _Float16* h16     = (_Float16*)(ws + NW_H16);
        _Float16* wc16    = (_Float16*)(ws + NW_WC16);
        float* bsum       = (float*)(ws + NW_BSUM);
        unsigned* bar     = (unsigned*)(ws + NW_BAR);
        _Float16* WinT    = (_Float16*)(ws + NW_WINT);
        _Float16* x16     = (_Float16*)(ws + NW_X16);
        _Float16* ctx_h   = (_Float16*)(ws + NW_CTXH);
        _Float16* ctxW    = (_Float16*)(ws + NW_CTXW);
        const int use_ring = (ws_size >= NW_RING_TOTAL) ? 1 : 0;
        _Float16* hyring  = (_Float16*)(ws + NW_HYRING);
        _Float16* wcring  = (_Float16*)(ws + NW_WCRING);

        k_bias<<<16, 256, 0, stream>>>(bih, bhh, bsum);
        k_zero<<<4, 256, 0, stream>>>(bar);
        k_cvt<<<2048, 256, 0, stream>>>(ctx, ctx_h, SS * BB * HH / 4);
        k_cvt<<<4096, 256, 0, stream>>>(x, x16, TT * BB * DD / 4);
        k_cvt<<<32, 256, 0, stream>>>(h0, h16, BB * HH / 4);
        k_trwin<<<1024, 256, 0, stream>>>(Win, WinT);
        k_ctxw<<<1024, 256, 0, stream>>>(ctx, WinT, ctxW);

        k_persist<<<256, 512, 0, stream>>>(x16, ctx_h, ctxW, Whh, Wih, Wout, bsum,
                                           h0, c0, cbuf, h16, hy16, wc16,
                                           hyring, wcring, scores, out, bar, use_ring);

        float* hT = out + (size_t)TT * BB * HH;
        float* cT = hT + BB * HH;
        k_fin<<<128, 256, 0, stream>>>(out + (size_t)(TT - 1) * BB * HH, cbuf, hT, cT);
        return;
    }

    // ---------------- old path (fallback, unchanged) ----------------
    float* cbuf   = (float*)(ws + 0);        // 131072
    float* hy     = (float*)(ws + 131072);   // 131072
    float* target = (float*)(ws + 262144);   // 131072
    float* scores = (float*)(ws + 393216);   //  65536
    float* wc     = (float*)(ws + 458752);   // 131072
    float* bsum   = (float*)(ws + 589824);   //  16384
    _Float16* Whh_h  = (_Float16*)(ws + 606208);    //  8388608
    _Float16* Win_h  = (_Float16*)(ws + 8994816);   //  2097152
    _Float16* Wout_h = (_Float16*)(ws + 11091968);  //  4194304
    _Float16* Wih_h  = (_Float16*)(ws + 15286272);  //  8388608
    _Float16* ctx_h  = (_Float16*)(ws + 23674880);  // 33554432
    _Float16* gx     = (_Float16*)(ws + 57229312);  // 134217728

    const int staged  = (ws_size >= (size_t)57229312) ? 1 : 0;
    const int use_pre = (ws_size >= (size_t)191447040) ? 1 : 0;

    k_bias<<<16, 256, 0, stream>>>(bih, bhh, bsum);
    k_init<<<128, 256, 0, stream>>>(c0, cbuf);
    if (staged) {
        k_cvt<<<1024, 256, 0, stream>>>(Whh, Whh_h, 4 * HH * HH / 4);
        k_cvt<<<1024, 256, 0, stream>>>(Win, Win_h, HH * HH / 4);
        k_cvt<<<1024, 256, 0, stream>>>(Wout, Wout_h, 2 * HH * HH / 4);
        k_cvt<<<2048, 256, 0, stream>>>(ctx, ctx_h, SS * BB * HH / 4);
        if (!use_pre) k_cvt<<<1024, 256, 0, stream>>>(Wih, Wih_h, 4 * HH * DD / 4);
    }
    if (use_pre) k_pre<<<4096, 256, 0, stream>>>(x, Wih, gx);

    for (int t = 0; t < TT; ++t) {
        const float* hprev = (t == 0) ? h0 : (out + (size_t)(t - 1) * BB * HH);
        const _Float16* gx_t = gx + (size_t)t * BB * 4 * HH;
        const float* xt = x + (size_t)t * BB * DD;
        float* out_t = out + (size_t)t * BB * HH;

        k_step1<<<128, 64, 0, stream>>>(hprev, Whh_h, Whh, gx_t, xt, Wih_h, Wih,
                                        bsum, cbuf, hy, use_pre, staged);
        k_target<<<128, 64, 0, stream>>>(hy, Win_h, Win, target, staged);
        k_scores<<<4096, 256, 0, stream>>>(ctx_h, ctx, target, scores, staged);
        k_attn<<<64, 256, 0, stream>>>(ctx_h, ctx, scores, wc, staged);
        k_out<<<128, 64, 0, stream>>>(wc, hy, Wout_h, Wout, out_t, staged);
    }

    float* hT = out + (size_t)TT * BB * HH;
    float* cT = hT + BB * HH;
    k_fin<<<128, 256, 0, stream>>>(out + (size_t)(TT - 1) * BB * HH, cbuf, hT, cT);
}